// Round 7
// baseline (296.297 us; speedup 1.0000x reference)
//
#include <hip/hip_runtime.h>

#define TPB 256
constexpr int DIN = 47;
constexpr int HID = 128;
constexpr int LAT = 64;
constexpr int GG  = 1024;

typedef __attribute__((ext_vector_type(8))) short short8v;
typedef __attribute__((ext_vector_type(4))) float float4v;

__device__ inline ushort f2bf(float f) {          // round-to-nearest-even bf16
  uint32_t u = __float_as_uint(f);
  return (ushort)((u + 0x7FFFu + ((u >> 16) & 1u)) >> 16);
}
__device__ inline float bf2f(ushort s) {
  return __uint_as_float(((uint32_t)s) << 16);
}

// ---------------- embed: out(bf16) = relu(x @ W_emb + b), x:[n,47] fp32 ----------------
__global__ __launch_bounds__(256) void embed_kernel(
    const float* __restrict__ x, const float* __restrict__ W,
    const float* __restrict__ b, ushort* __restrict__ out, int n) {
  __shared__ float Wl[DIN * HID];
  __shared__ float bl[HID];
  __shared__ float xs[8][48];
  const int tid = threadIdx.x;
  for (int i = tid; i < DIN * HID; i += TPB) Wl[i] = W[i];
  if (tid < HID) bl[tid] = b[tid];
  const int tx = tid & 31, slot = tid >> 5;
  const float4* Wl4 = (const float4*)Wl;
  for (int base = blockIdx.x * 8; base < n; base += gridDim.x * 8) {
    __syncthreads();
    for (int i = tid; i < 8 * DIN; i += TPB) {
      int s = i / DIN, k = i - s * DIN;
      int node = base + s;
      xs[s][k] = (node < n) ? x[node * DIN + k] : 0.f;
    }
    __syncthreads();
    int node = base + slot;
    if (node < n) {
      float4 acc = ((const float4*)bl)[tx];
      #pragma unroll
      for (int k = 0; k < DIN; ++k) {
        float xv = xs[slot][k];
        float4 w = Wl4[k * 32 + tx];
        acc.x += xv * w.x; acc.y += xv * w.y; acc.z += xv * w.z; acc.w += xv * w.w;
      }
      ushort4 o;
      o.x = f2bf(fmaxf(acc.x, 0.f)); o.y = f2bf(fmaxf(acc.y, 0.f));
      o.z = f2bf(fmaxf(acc.z, 0.f)); o.w = f2bf(fmaxf(acc.w, 0.f));
      ((ushort4*)out)[node * 32 + tx] = o;
    }
  }
}

// ------- lin (MFMA): out[n,OD] bf16 = h[n,128] bf16 @ W[128,OD] fp32->bf16 -------
template <int OD>
__global__ __launch_bounds__(256) void lin_mfma_kernel(
    const ushort* __restrict__ h, const float* __restrict__ W,
    ushort* __restrict__ out, int n) {
  __shared__ ushort Wt[OD * 128];   // [col][k] bf16, swizzled
  const int tid = threadIdx.x;
  for (int idx = tid; idx < 128 * OD; idx += TPB) {
    int k = idx / OD, c = idx - k * OD;      // W row-major read, coalesced
    Wt[c * 128 + (k ^ ((c & 7) << 3))] = f2bf(W[idx]);
  }
  __syncthreads();
  const int lane = tid & 63, wave = tid >> 6;
  const int rowA = lane & 15, kgrp = lane >> 4;
  const int nb0 = blockIdx.x * 64 + wave * 16;
  int nodeA = nb0 + rowA; if (nodeA >= n) nodeA = n - 1;
  const ushort* hrow = h + (size_t)nodeA * 128 + kgrp * 8;
  short8v a0 = *(const short8v*)(hrow);
  short8v a1 = *(const short8v*)(hrow + 32);
  short8v a2 = *(const short8v*)(hrow + 64);
  short8v a3 = *(const short8v*)(hrow + 96);
  #pragma unroll
  for (int ct = 0; ct < OD / 16; ++ct) {
    const int c = ct * 16 + rowA;
    const int sw = (c & 7) << 3;
    const ushort* wc = &Wt[c * 128];
    float4v acc = {0.f, 0.f, 0.f, 0.f};
    acc = __builtin_amdgcn_mfma_f32_16x16x32_bf16(a0, *(const short8v*)(wc + ((kgrp * 8)       ^ sw)), acc, 0, 0, 0);
    acc = __builtin_amdgcn_mfma_f32_16x16x32_bf16(a1, *(const short8v*)(wc + ((kgrp * 8 + 32)  ^ sw)), acc, 0, 0, 0);
    acc = __builtin_amdgcn_mfma_f32_16x16x32_bf16(a2, *(const short8v*)(wc + ((kgrp * 8 + 64)  ^ sw)), acc, 0, 0, 0);
    acc = __builtin_amdgcn_mfma_f32_16x16x32_bf16(a3, *(const short8v*)(wc + ((kgrp * 8 + 96)  ^ sw)), acc, 0, 0, 0);
    #pragma unroll
    for (int r = 0; r < 4; ++r) {
      int node = nb0 + kgrp * 4 + r;
      if (node < n) out[(size_t)node * OD + c] = f2bf(acc[r]);
    }
  }
}

// ---------------- CSR build ----------------
__global__ void deg_rank_kernel(const int* __restrict__ dst, int* __restrict__ cnt,
                                int* __restrict__ rank, int e) {
  int i = blockIdx.x * TPB + threadIdx.x;
  if (i < e) rank[i] = atomicAdd(&cnt[dst[i]], 1);
}

__global__ void dinv_kernel(const int* __restrict__ cnt, float* __restrict__ dinv, int n) {
  int i = blockIdx.x * TPB + threadIdx.x;
  if (i < n) dinv[i] = rsqrtf((float)cnt[i] + 1.f);
}

__global__ void scan1_kernel(const int* __restrict__ cnt, int* __restrict__ rowptr,
                             int* __restrict__ bsum, int n) {
  __shared__ int sh[TPB];
  int i = blockIdx.x * TPB + threadIdx.x;
  int v = (i < n) ? cnt[i] : 0;
  sh[threadIdx.x] = v;
  __syncthreads();
  for (int off = 1; off < TPB; off <<= 1) {
    int t = (threadIdx.x >= off) ? sh[threadIdx.x - off] : 0;
    __syncthreads();
    sh[threadIdx.x] += t;
    __syncthreads();
  }
  if (i < n) rowptr[i] = sh[threadIdx.x] - v;
  if (threadIdx.x == TPB - 1) bsum[blockIdx.x] = sh[threadIdx.x];
}

__global__ void scan2_kernel(int* __restrict__ bsum, int nb) {
  __shared__ int sh[512];
  __shared__ int carry;
  if (threadIdx.x == 0) carry = 0;
  __syncthreads();
  for (int base = 0; base < nb; base += 512) {
    int i = base + threadIdx.x;
    int v = (i < nb) ? bsum[i] : 0;
    sh[threadIdx.x] = v;
    __syncthreads();
    for (int off = 1; off < 512; off <<= 1) {
      int t = (threadIdx.x >= off) ? sh[threadIdx.x - off] : 0;
      __syncthreads();
      sh[threadIdx.x] += t;
      __syncthreads();
    }
    if (i < nb) bsum[i] = carry + sh[threadIdx.x] - v;
    __syncthreads();
    if (threadIdx.x == 0) carry += sh[511];
    __syncthreads();
  }
}

__global__ void scan3_kernel(int* __restrict__ rowptr, const int* __restrict__ bsum,
                             int n, int e) {
  int i = blockIdx.x * TPB + threadIdx.x;
  if (i < n) rowptr[i] += bsum[blockIdx.x];
  if (i == 0) rowptr[n] = e;
}

__global__ void place_kernel(const int* __restrict__ src, const int* __restrict__ dst,
                             const int* __restrict__ rowptr, const int* __restrict__ rank,
                             int* __restrict__ csr_src, int e) {
  int i = blockIdx.x * TPB + threadIdx.x;
  if (i >= e) return;
  csr_src[rowptr[dst[i]] + rank[i]] = src[i];
}

// --- gather bf16 rows, deep-unrolled (8 rows in flight), fused finalize, bf16 out ---
template <int OD>
__global__ __launch_bounds__(256) void gather_kernel(
    const ushort* __restrict__ hlin, const int* __restrict__ rowptr,
    const int* __restrict__ csr_src, const float* __restrict__ dinv,
    const float* __restrict__ b, ushort* __restrict__ out, int n) {
  constexpr int Q  = OD / 4;
  constexpr int NS = TPB / Q;
  const int tid = threadIdx.x;
  const int tx = tid & (Q - 1), slot = tid / Q;
  int node = blockIdx.x * NS + slot;
  if (node >= n) return;
  const ushort4* h4 = (const ushort4*)hlin;
  int start = rowptr[node], end = rowptr[node + 1];
  float di = dinv[node];
  float ax = 0.f, ay = 0.f, az = 0.f, aw = 0.f;
  int j = start;
  for (; j + 7 < end; j += 8) {           // 8 rows in flight
    int s[8];
    float w[8];
    ushort4 v[8];
    #pragma unroll
    for (int u = 0; u < 8; ++u) s[u] = csr_src[j + u];
    #pragma unroll
    for (int u = 0; u < 8; ++u) v[u] = h4[(size_t)s[u] * Q + tx];
    #pragma unroll
    for (int u = 0; u < 8; ++u) w[u] = dinv[s[u]] * di;
    #pragma unroll
    for (int u = 0; u < 8; ++u) {
      ax += bf2f(v[u].x) * w[u];
      ay += bf2f(v[u].y) * w[u];
      az += bf2f(v[u].z) * w[u];
      aw += bf2f(v[u].w) * w[u];
    }
  }
  for (; j + 3 < end; j += 4) {
    int s[4];
    float w[4];
    ushort4 v[4];
    #pragma unroll
    for (int u = 0; u < 4; ++u) s[u] = csr_src[j + u];
    #pragma unroll
    for (int u = 0; u < 4; ++u) v[u] = h4[(size_t)s[u] * Q + tx];
    #pragma unroll
    for (int u = 0; u < 4; ++u) w[u] = dinv[s[u]] * di;
    #pragma unroll
    for (int u = 0; u < 4; ++u) {
      ax += bf2f(v[u].x) * w[u];
      ay += bf2f(v[u].y) * w[u];
      az += bf2f(v[u].z) * w[u];
      aw += bf2f(v[u].w) * w[u];
    }
  }
  for (; j < end; ++j) {
    int s0 = csr_src[j];
    float w0 = dinv[s0] * di;
    ushort4 v0 = h4[(size_t)s0 * Q + tx];
    ax += bf2f(v0.x) * w0; ay += bf2f(v0.y) * w0;
    az += bf2f(v0.z) * w0; aw += bf2f(v0.w) * w0;
  }
  float sw = di * di;
  ushort4 hv = h4[(size_t)node * Q + tx];
  float4 bv = ((const float4*)b)[tx];
  ushort4 o;
  o.x = f2bf(fmaxf(ax + bf2f(hv.x) * sw + bv.x, 0.f));
  o.y = f2bf(fmaxf(ay + bf2f(hv.y) * sw + bv.y, 0.f));
  o.z = f2bf(fmaxf(az + bf2f(hv.z) * sw + bv.z, 0.f));
  o.w = f2bf(fmaxf(aw + bf2f(hv.w) * sw + bv.w, 0.f));
  ((ushort4*)out)[(size_t)node * Q + tx] = o;
}

// ---------------- pool: batch sorted -> segment mean (bf16 in, fp32 out) ----------------
__global__ void gstart_kernel(const int* __restrict__ batch, int* __restrict__ gstart,
                              int n, int G) {
  int i = blockIdx.x * TPB + threadIdx.x;
  if (i >= n) return;
  int bi = batch[i];
  int bp = (i == 0) ? -1 : batch[i - 1];
  for (int g = bp + 1; g <= bi; ++g) gstart[g] = i;
  if (i == n - 1)
    for (int g = bi + 1; g <= G; ++g) gstart[g] = n;
}

__global__ __launch_bounds__(256) void pool2_kernel(
    const ushort* __restrict__ h, const int* __restrict__ gstart,
    float* __restrict__ out) {
  __shared__ float sh[4][LAT];
  int g = blockIdx.x;
  int s = gstart[g], epos = gstart[g + 1];
  int c = threadIdx.x & (LAT - 1), r = threadIdx.x >> 6;
  float acc = 0.f;
  for (int i = s + r; i < epos; i += 4)
    acc += bf2f(h[(size_t)i * LAT + c]);
  sh[r][c] = acc;
  __syncthreads();
  if (r == 0) {
    float v = sh[0][c] + sh[1][c] + sh[2][c] + sh[3][c];
    out[(size_t)g * LAT + c] = v / fmaxf((float)(epos - s), 1.f);
  }
}

extern "C" void kernel_launch(void* const* d_in, const int* in_sizes, int n_in,
                              void* d_out, int out_size, void* d_ws, size_t ws_size,
                              hipStream_t stream) {
  const float* x     = (const float*)d_in[0];
  const float* W_emb = (const float*)d_in[1];
  const float* b_emb = (const float*)d_in[2];
  const float* W1    = (const float*)d_in[3];
  const float* b1    = (const float*)d_in[4];
  const float* W2    = (const float*)d_in[5];
  const float* b2    = (const float*)d_in[6];
  const int*   ei    = (const int*)d_in[7];
  const int*   batch = (const int*)d_in[8];
  const int n = in_sizes[8];
  const int e = in_sizes[7] / 2;
  const int* srcp = ei;
  const int* dstp = ei + e;
  float* out = (float*)d_out;

  char* ws = (char*)d_ws;
  size_t off = 0;
  auto alloc = [&](size_t bytes) {
    void* p = ws + off;
    off += (bytes + 255) & ~(size_t)255;
    return p;
  };
  ushort* bufA    = (ushort*)alloc((size_t)n * HID * 2);   // h0 / h1 / h2 (bf16)
  ushort* bufB    = (ushort*)alloc((size_t)n * HID * 2);   // hlin (bf16)
  float*  dinv    = (float*)alloc((size_t)n * 4);
  int*    cnt     = (int*)alloc((size_t)n * 4);
  int*    rowptr  = (int*)alloc((size_t)(n + 1) * 4);
  int*    bsum    = (int*)alloc((size_t)512 * 4);
  int*    rank    = (int*)alloc((size_t)e * 4);
  int*    csr_src = (int*)alloc((size_t)e * 4);
  int*    gstart  = (int*)alloc((size_t)(GG + 1) * 4);

  const int nb = (n + TPB - 1) / TPB;
  const int eb = (e + TPB - 1) / TPB;
  const int mb = (n + 63) / 64;

  hipMemsetAsync(cnt, 0, (size_t)n * 4, stream);

  // h0 = relu(x @ W_emb + b_emb) -> bufA (bf16)
  embed_kernel<<<2048, TPB, 0, stream>>>(x, W_emb, b_emb, bufA, n);

  // CSR by dst (counting sort, atomic-free placement) + dinv
  deg_rank_kernel<<<eb, TPB, 0, stream>>>(dstp, cnt, rank, e);
  dinv_kernel<<<nb, TPB, 0, stream>>>(cnt, dinv, n);
  scan1_kernel<<<nb, TPB, 0, stream>>>(cnt, rowptr, bsum, n);
  scan2_kernel<<<1, 512, 0, stream>>>(bsum, nb);
  scan3_kernel<<<nb, TPB, 0, stream>>>(rowptr, bsum, n, e);
  place_kernel<<<eb, TPB, 0, stream>>>(srcp, dstp, rowptr, rank, csr_src, e);

  // graph segment starts (batch sorted)
  gstart_kernel<<<nb, TPB, 0, stream>>>(batch, gstart, n, GG);

  // conv1: MFMA lin -> bufB; gather(+self+bias+relu) -> bufA
  lin_mfma_kernel<HID><<<mb, TPB, 0, stream>>>(bufA, W1, bufB, n);
  gather_kernel<HID><<<(n * (HID / 4) + TPB - 1) / TPB, TPB, 0, stream>>>(
      bufB, rowptr, csr_src, dinv, b1, bufA, n);

  // conv2: MFMA lin -> bufB (n x 64); gather -> bufA (n x 64)
  lin_mfma_kernel<LAT><<<mb, TPB, 0, stream>>>(bufA, W2, bufB, n);
  gather_kernel<LAT><<<(n * (LAT / 4) + TPB - 1) / TPB, TPB, 0, stream>>>(
      bufB, rowptr, csr_src, dinv, b2, bufA, n);

  // mean pool
  pool2_kernel<<<GG, TPB, 0, stream>>>(bufA, gstart, out);
}

// Round 8
// 264.138 us; speedup vs baseline: 1.1217x; 1.1217x over previous
//
#include <hip/hip_runtime.h>

#define TPB 256
constexpr int DIN = 47;
constexpr int HID = 128;
constexpr int LAT = 64;
constexpr int GG  = 1024;

typedef __attribute__((ext_vector_type(8))) short short8v;
typedef __attribute__((ext_vector_type(4))) float float4v;

__device__ inline ushort f2bf(float f) {          // round-to-nearest-even bf16
  uint32_t u = __float_as_uint(f);
  return (ushort)((u + 0x7FFFu + ((u >> 16) & 1u)) >> 16);
}
__device__ inline float bf2f(ushort s) {
  return __uint_as_float(((uint32_t)s) << 16);
}

// ---------------- embed: out(bf16) = relu(x @ W_emb + b); also zeroes cnt ----------------
__global__ __launch_bounds__(256) void embed_kernel(
    const float* __restrict__ x, const float* __restrict__ W,
    const float* __restrict__ b, ushort* __restrict__ out,
    int* __restrict__ cnt, int n) {
  // zero cnt (replaces hipMemsetAsync dispatch)
  for (int i = blockIdx.x * TPB + threadIdx.x; i < n; i += gridDim.x * TPB) cnt[i] = 0;
  __shared__ float Wl[DIN * HID];
  __shared__ float bl[HID];
  __shared__ float xs[8][48];
  const int tid = threadIdx.x;
  for (int i = tid; i < DIN * HID; i += TPB) Wl[i] = W[i];
  if (tid < HID) bl[tid] = b[tid];
  const int tx = tid & 31, slot = tid >> 5;
  const float4* Wl4 = (const float4*)Wl;
  for (int base = blockIdx.x * 8; base < n; base += gridDim.x * 8) {
    __syncthreads();
    for (int i = tid; i < 8 * DIN; i += TPB) {
      int s = i / DIN, k = i - s * DIN;
      int node = base + s;
      xs[s][k] = (node < n) ? x[node * DIN + k] : 0.f;
    }
    __syncthreads();
    int node = base + slot;
    if (node < n) {
      float4 acc = ((const float4*)bl)[tx];
      #pragma unroll
      for (int k = 0; k < DIN; ++k) {
        float xv = xs[slot][k];
        float4 w = Wl4[k * 32 + tx];
        acc.x += xv * w.x; acc.y += xv * w.y; acc.z += xv * w.z; acc.w += xv * w.w;
      }
      ushort4 o;
      o.x = f2bf(fmaxf(acc.x, 0.f)); o.y = f2bf(fmaxf(acc.y, 0.f));
      o.z = f2bf(fmaxf(acc.z, 0.f)); o.w = f2bf(fmaxf(acc.w, 0.f));
      ((ushort4*)out)[node * 32 + tx] = o;
    }
  }
}

// ------- lin (MFMA): out[n,OD] bf16 = h[n,128] bf16 @ W[128,OD] fp32->bf16 -------
template <int OD>
__global__ __launch_bounds__(256) void lin_mfma_kernel(
    const ushort* __restrict__ h, const float* __restrict__ W,
    ushort* __restrict__ out, int n) {
  __shared__ ushort Wt[OD * 128];   // [col][k] bf16, swizzled
  const int tid = threadIdx.x;
  for (int idx = tid; idx < 128 * OD; idx += TPB) {
    int k = idx / OD, c = idx - k * OD;
    Wt[c * 128 + (k ^ ((c & 7) << 3))] = f2bf(W[idx]);
  }
  __syncthreads();
  const int lane = tid & 63, wave = tid >> 6;
  const int rowA = lane & 15, kgrp = lane >> 4;
  const int nb0 = blockIdx.x * 64 + wave * 16;
  int nodeA = nb0 + rowA; if (nodeA >= n) nodeA = n - 1;
  const ushort* hrow = h + (size_t)nodeA * 128 + kgrp * 8;
  short8v a0 = *(const short8v*)(hrow);
  short8v a1 = *(const short8v*)(hrow + 32);
  short8v a2 = *(const short8v*)(hrow + 64);
  short8v a3 = *(const short8v*)(hrow + 96);
  #pragma unroll
  for (int ct = 0; ct < OD / 16; ++ct) {
    const int c = ct * 16 + rowA;
    const int sw = (c & 7) << 3;
    const ushort* wc = &Wt[c * 128];
    float4v acc = {0.f, 0.f, 0.f, 0.f};
    acc = __builtin_amdgcn_mfma_f32_16x16x32_bf16(a0, *(const short8v*)(wc + ((kgrp * 8)       ^ sw)), acc, 0, 0, 0);
    acc = __builtin_amdgcn_mfma_f32_16x16x32_bf16(a1, *(const short8v*)(wc + ((kgrp * 8 + 32)  ^ sw)), acc, 0, 0, 0);
    acc = __builtin_amdgcn_mfma_f32_16x16x32_bf16(a2, *(const short8v*)(wc + ((kgrp * 8 + 64)  ^ sw)), acc, 0, 0, 0);
    acc = __builtin_amdgcn_mfma_f32_16x16x32_bf16(a3, *(const short8v*)(wc + ((kgrp * 8 + 96)  ^ sw)), acc, 0, 0, 0);
    #pragma unroll
    for (int r = 0; r < 4; ++r) {
      int node = nb0 + kgrp * 4 + r;
      if (node < n) out[(size_t)node * OD + c] = f2bf(acc[r]);
    }
  }
}

// ------- quant: bf16 rows -> biased int8 rows + scale, sdinv = scale*dinv -------
template <int OD>
__global__ __launch_bounds__(256) void quant_kernel(
    const ushort* __restrict__ hlin, unsigned char* __restrict__ q,
    float* __restrict__ scale, float* __restrict__ sdinv,
    const float* __restrict__ dinv, int n) {
  constexpr int CPL = OD / 16;                 // cols per lane: 8 or 4
  const int tid = threadIdx.x;
  const int grp = tid >> 4, L = tid & 15;
  for (int row = blockIdx.x * 16 + grp; row < n; row += gridDim.x * 16) {
    const ushort* hr = hlin + (size_t)row * OD + CPL * L;
    float v[CPL];
    #pragma unroll
    for (int c = 0; c < CPL; ++c) v[c] = bf2f(hr[c]);
    float m = 0.f;
    #pragma unroll
    for (int c = 0; c < CPL; ++c) m = fmaxf(m, fabsf(v[c]));
    #pragma unroll
    for (int o = 1; o < 16; o <<= 1) m = fmaxf(m, __shfl_xor(m, o, 16));
    float inv = (m > 0.f) ? 127.f / m : 0.f;
    unsigned int pk[CPL / 4];
    #pragma unroll
    for (int wq = 0; wq < CPL / 4; ++wq) {
      unsigned int p = 0;
      #pragma unroll
      for (int c = 0; c < 4; ++c) {
        int qv = (int)rintf(v[wq * 4 + c] * inv) + 128;
        p |= ((unsigned int)(qv & 255)) << (8 * c);
      }
      pk[wq] = p;
    }
    unsigned char* qr = q + (size_t)row * OD + CPL * L;
    if (CPL == 8) *(uint2*)qr = make_uint2(pk[0], pk[CPL / 4 - 1]);
    else          *(unsigned int*)qr = pk[0];
    if (L == 0) {
      float sc = m * (1.f / 127.f);
      scale[row] = sc;
      sdinv[row] = sc * dinv[row];
    }
  }
}

// ---------------- CSR build ----------------
__global__ void deg_rank_kernel(const int* __restrict__ dst, int* __restrict__ cnt,
                                int* __restrict__ rank, int e) {
  int i = blockIdx.x * TPB + threadIdx.x;
  if (i < e) rank[i] = atomicAdd(&cnt[dst[i]], 1);
}

// scan1 + dinv fused
__global__ void scan1_kernel(const int* __restrict__ cnt, int* __restrict__ rowptr,
                             int* __restrict__ bsum, float* __restrict__ dinv, int n) {
  __shared__ int sh[TPB];
  int i = blockIdx.x * TPB + threadIdx.x;
  int v = (i < n) ? cnt[i] : 0;
  if (i < n) dinv[i] = rsqrtf((float)v + 1.f);
  sh[threadIdx.x] = v;
  __syncthreads();
  for (int off = 1; off < TPB; off <<= 1) {
    int t = (threadIdx.x >= off) ? sh[threadIdx.x - off] : 0;
    __syncthreads();
    sh[threadIdx.x] += t;
    __syncthreads();
  }
  if (i < n) rowptr[i] = sh[threadIdx.x] - v;
  if (threadIdx.x == TPB - 1) bsum[blockIdx.x] = sh[threadIdx.x];
}

__global__ void scan2_kernel(int* __restrict__ bsum, int nb) {
  __shared__ int sh[512];
  __shared__ int carry;
  if (threadIdx.x == 0) carry = 0;
  __syncthreads();
  for (int base = 0; base < nb; base += 512) {
    int i = base + threadIdx.x;
    int v = (i < nb) ? bsum[i] : 0;
    sh[threadIdx.x] = v;
    __syncthreads();
    for (int off = 1; off < 512; off <<= 1) {
      int t = (threadIdx.x >= off) ? sh[threadIdx.x - off] : 0;
      __syncthreads();
      sh[threadIdx.x] += t;
      __syncthreads();
    }
    if (i < nb) bsum[i] = carry + sh[threadIdx.x] - v;
    __syncthreads();
    if (threadIdx.x == 0) carry += sh[511];
    __syncthreads();
  }
}

__global__ void scan3_kernel(int* __restrict__ rowptr, const int* __restrict__ bsum,
                             int n, int e) {
  int i = blockIdx.x * TPB + threadIdx.x;
  if (i < n) rowptr[i] += bsum[blockIdx.x];
  if (i == 0) rowptr[n] = e;
}

// place + gstart fused (grid covers e >= n)
__global__ void place_kernel(const int* __restrict__ src, const int* __restrict__ dst,
                             const int* __restrict__ rowptr, const int* __restrict__ rank,
                             int* __restrict__ csr_src,
                             const int* __restrict__ batch, int* __restrict__ gstart,
                             int n, int G, int e) {
  int i = blockIdx.x * TPB + threadIdx.x;
  if (i < e) csr_src[rowptr[dst[i]] + rank[i]] = src[i];
  if (i < n) {
    int bi = batch[i];
    int bp = (i == 0) ? -1 : batch[i - 1];
    for (int g = bp + 1; g <= bi; ++g) gstart[g] = i;
    if (i == n - 1)
      for (int g = bi + 1; g <= G; ++g) gstart[g] = n;
  }
}

// --- gather int8 rows (biased +128), fused finalize, bf16 out ---
template <int OD>
__global__ __launch_bounds__(256) void gather_i8_kernel(
    const unsigned char* __restrict__ q, const float* __restrict__ scale,
    const float* __restrict__ sdinv, const int* __restrict__ rowptr,
    const int* __restrict__ csr_src, const float* __restrict__ dinv,
    const float* __restrict__ b, ushort* __restrict__ out, int n) {
  constexpr int Q8 = OD / 8;                    // threads per node (16 or 8)
  constexpr int NS = TPB / Q8;
  const int tid = threadIdx.x;
  const int tx = tid & (Q8 - 1), slot = tid / Q8;
  int node = blockIdx.x * NS + slot;
  if (node >= n) return;
  const uint2* qrow = (const uint2*)q;          // row stride = Q8 uint2
  int start = rowptr[node], end = rowptr[node + 1];
  float di = dinv[node];
  float acc[8];
  #pragma unroll
  for (int c = 0; c < 8; ++c) acc[c] = 0.f;
  float wsum = 0.f;
  int j = start;
  for (; j + 3 < end; j += 4) {
    int s[4]; uint2 v[4]; float w[4];
    #pragma unroll
    for (int u = 0; u < 4; ++u) s[u] = csr_src[j + u];
    #pragma unroll
    for (int u = 0; u < 4; ++u) v[u] = qrow[(size_t)s[u] * Q8 + tx];
    #pragma unroll
    for (int u = 0; u < 4; ++u) w[u] = sdinv[s[u]] * di;
    #pragma unroll
    for (int u = 0; u < 4; ++u) {
      wsum += w[u];
      acc[0] += w[u] * (float)( v[u].x        & 255u);
      acc[1] += w[u] * (float)((v[u].x >>  8) & 255u);
      acc[2] += w[u] * (float)((v[u].x >> 16) & 255u);
      acc[3] += w[u] * (float)( v[u].x >> 24);
      acc[4] += w[u] * (float)( v[u].y        & 255u);
      acc[5] += w[u] * (float)((v[u].y >>  8) & 255u);
      acc[6] += w[u] * (float)((v[u].y >> 16) & 255u);
      acc[7] += w[u] * (float)( v[u].y >> 24);
    }
  }
  for (; j < end; ++j) {
    int s0 = csr_src[j];
    uint2 v0 = qrow[(size_t)s0 * Q8 + tx];
    float w0 = sdinv[s0] * di;
    wsum += w0;
    acc[0] += w0 * (float)( v0.x        & 255u);
    acc[1] += w0 * (float)((v0.x >>  8) & 255u);
    acc[2] += w0 * (float)((v0.x >> 16) & 255u);
    acc[3] += w0 * (float)( v0.x >> 24);
    acc[4] += w0 * (float)( v0.y        & 255u);
    acc[5] += w0 * (float)((v0.y >>  8) & 255u);
    acc[6] += w0 * (float)((v0.y >> 16) & 255u);
    acc[7] += w0 * (float)( v0.y >> 24);
  }
  // self term + bias + relu
  uint2 sv = qrow[(size_t)node * Q8 + tx];
  float ss = scale[node] * di * di;
  float su[8];
  su[0] = (float)( sv.x        & 255u); su[1] = (float)((sv.x >>  8) & 255u);
  su[2] = (float)((sv.x >> 16) & 255u); su[3] = (float)( sv.x >> 24);
  su[4] = (float)( sv.y        & 255u); su[5] = (float)((sv.y >>  8) & 255u);
  su[6] = (float)((sv.y >> 16) & 255u); su[7] = (float)( sv.y >> 24);
  float4 b0 = *(const float4*)(b + 8 * tx);
  float4 b1 = *(const float4*)(b + 8 * tx + 4);
  float bb[8] = {b0.x, b0.y, b0.z, b0.w, b1.x, b1.y, b1.z, b1.w};
  short8v o;
  #pragma unroll
  for (int c = 0; c < 8; ++c) {
    float val = acc[c] - 128.f * wsum + ss * (su[c] - 128.f) + bb[c];
    o[c] = (short)f2bf(fmaxf(val, 0.f));
  }
  *(short8v*)(out + (size_t)node * OD + 8 * tx) = o;
}

// ---------------- pool: batch sorted -> segment mean (bf16 in, fp32 out) ----------------
__global__ __launch_bounds__(256) void pool2_kernel(
    const ushort* __restrict__ h, const int* __restrict__ gstart,
    float* __restrict__ out) {
  __shared__ float sh[4][LAT];
  int g = blockIdx.x;
  int s = gstart[g], epos = gstart[g + 1];
  int c = threadIdx.x & (LAT - 1), r = threadIdx.x >> 6;
  float acc = 0.f;
  for (int i = s + r; i < epos; i += 4)
    acc += bf2f(h[(size_t)i * LAT + c]);
  sh[r][c] = acc;
  __syncthreads();
  if (r == 0) {
    float v = sh[0][c] + sh[1][c] + sh[2][c] + sh[3][c];
    out[(size_t)g * LAT + c] = v / fmaxf((float)(epos - s), 1.f);
  }
}

extern "C" void kernel_launch(void* const* d_in, const int* in_sizes, int n_in,
                              void* d_out, int out_size, void* d_ws, size_t ws_size,
                              hipStream_t stream) {
  const float* x     = (const float*)d_in[0];
  const float* W_emb = (const float*)d_in[1];
  const float* b_emb = (const float*)d_in[2];
  const float* W1    = (const float*)d_in[3];
  const float* b1    = (const float*)d_in[4];
  const float* W2    = (const float*)d_in[5];
  const float* b2    = (const float*)d_in[6];
  const int*   ei    = (const int*)d_in[7];
  const int*   batch = (const int*)d_in[8];
  const int n = in_sizes[8];
  const int e = in_sizes[7] / 2;
  const int* srcp = ei;
  const int* dstp = ei + e;
  float* out = (float*)d_out;

  char* ws = (char*)d_ws;
  size_t off = 0;
  auto alloc = [&](size_t bytes) {
    void* p = ws + off;
    off += (bytes + 255) & ~(size_t)255;
    return p;
  };
  ushort* bufA    = (ushort*)alloc((size_t)n * HID * 2);        // h0/h1/h2 bf16
  ushort* bufB    = (ushort*)alloc((size_t)n * HID * 2);        // hlin bf16
  unsigned char* bufQ = (unsigned char*)alloc((size_t)n * HID); // int8 rows
  float*  scaleq  = (float*)alloc((size_t)n * 4);
  float*  sdinv   = (float*)alloc((size_t)n * 4);
  float*  dinv    = (float*)alloc((size_t)n * 4);
  int*    cnt     = (int*)alloc((size_t)n * 4);
  int*    rowptr  = (int*)alloc((size_t)(n + 1) * 4);
  int*    bsum    = (int*)alloc((size_t)512 * 4);
  int*    rank    = (int*)alloc((size_t)e * 4);
  int*    csr_src = (int*)alloc((size_t)e * 4);
  int*    gstart  = (int*)alloc((size_t)(GG + 1) * 4);

  const int nb = (n + TPB - 1) / TPB;
  const int eb = (e + TPB - 1) / TPB;
  const int mb = (n + 63) / 64;

  // h0 = relu(x @ W_emb + b_emb) -> bufA ; zero cnt
  embed_kernel<<<2048, TPB, 0, stream>>>(x, W_emb, b_emb, bufA, cnt, n);

  // CSR by dst + dinv
  deg_rank_kernel<<<eb, TPB, 0, stream>>>(dstp, cnt, rank, e);
  scan1_kernel<<<nb, TPB, 0, stream>>>(cnt, rowptr, bsum, dinv, n);
  scan2_kernel<<<1, 512, 0, stream>>>(bsum, nb);
  scan3_kernel<<<nb, TPB, 0, stream>>>(rowptr, bsum, n, e);
  place_kernel<<<eb, TPB, 0, stream>>>(srcp, dstp, rowptr, rank, csr_src,
                                       batch, gstart, n, GG, e);

  // conv1: lin -> bufB; quant -> bufQ; gather(int8) -> bufA
  lin_mfma_kernel<HID><<<mb, TPB, 0, stream>>>(bufA, W1, bufB, n);
  quant_kernel<HID><<<2048, TPB, 0, stream>>>(bufB, bufQ, scaleq, sdinv, dinv, n);
  gather_i8_kernel<HID><<<(n * (HID / 8) + TPB - 1) / TPB, TPB, 0, stream>>>(
      bufQ, scaleq, sdinv, rowptr, csr_src, dinv, b1, bufA, n);

  // conv2: lin -> bufB (n x 64); quant; gather(int8) -> bufA (n x 64)
  lin_mfma_kernel<LAT><<<mb, TPB, 0, stream>>>(bufA, W2, bufB, n);
  quant_kernel<LAT><<<2048, TPB, 0, stream>>>(bufB, bufQ, scaleq, sdinv, dinv, n);
  gather_i8_kernel<LAT><<<(n * (LAT / 8) + TPB - 1) / TPB, TPB, 0, stream>>>(
      bufQ, scaleq, sdinv, rowptr, csr_src, dinv, b2, bufA, n);

  // mean pool
  pool2_kernel<<<GG, TPB, 0, stream>>>(bufA, gstart, out);
}

// Round 9
// 263.331 us; speedup vs baseline: 1.1252x; 1.0031x over previous
//
#include <hip/hip_runtime.h>

#define TPB 256
constexpr int DIN = 47;
constexpr int HID = 128;
constexpr int LAT = 64;
constexpr int GG  = 1024;
constexpr int NR  = 8;     // histogram replicas (one per XCD)

typedef __attribute__((ext_vector_type(8))) short short8v;
typedef __attribute__((ext_vector_type(4))) float float4v;

__device__ inline ushort f2bf(float f) {          // round-to-nearest-even bf16
  uint32_t u = __float_as_uint(f);
  return (ushort)((u + 0x7FFFu + ((u >> 16) & 1u)) >> 16);
}
__device__ inline float bf2f(ushort s) {
  return __uint_as_float(((uint32_t)s) << 16);
}

// ---------------- embed: out(bf16) = relu(x @ W_emb + b); also zeroes cnt8 ----------------
__global__ __launch_bounds__(256) void embed_kernel(
    const float* __restrict__ x, const float* __restrict__ W,
    const float* __restrict__ b, ushort* __restrict__ out,
    int* __restrict__ cnt8, int n) {
  for (int i = blockIdx.x * TPB + threadIdx.x; i < NR * n; i += gridDim.x * TPB)
    cnt8[i] = 0;
  __shared__ float Wl[DIN * HID];
  __shared__ float bl[HID];
  __shared__ float xs[8][48];
  const int tid = threadIdx.x;
  for (int i = tid; i < DIN * HID; i += TPB) Wl[i] = W[i];
  if (tid < HID) bl[tid] = b[tid];
  const int tx = tid & 31, slot = tid >> 5;
  const float4* Wl4 = (const float4*)Wl;
  for (int base = blockIdx.x * 8; base < n; base += gridDim.x * 8) {
    __syncthreads();
    for (int i = tid; i < 8 * DIN; i += TPB) {
      int s = i / DIN, k = i - s * DIN;
      int node = base + s;
      xs[s][k] = (node < n) ? x[node * DIN + k] : 0.f;
    }
    __syncthreads();
    int node = base + slot;
    if (node < n) {
      float4 acc = ((const float4*)bl)[tx];
      #pragma unroll
      for (int k = 0; k < DIN; ++k) {
        float xv = xs[slot][k];
        float4 w = Wl4[k * 32 + tx];
        acc.x += xv * w.x; acc.y += xv * w.y; acc.z += xv * w.z; acc.w += xv * w.w;
      }
      ushort4 o;
      o.x = f2bf(fmaxf(acc.x, 0.f)); o.y = f2bf(fmaxf(acc.y, 0.f));
      o.z = f2bf(fmaxf(acc.z, 0.f)); o.w = f2bf(fmaxf(acc.w, 0.f));
      ((ushort4*)out)[node * 32 + tx] = o;
    }
  }
}

// ------- lin (MFMA): out[n,OD] bf16 = h[n,128] bf16 @ W[128,OD] fp32->bf16 -------
template <int OD>
__global__ __launch_bounds__(256) void lin_mfma_kernel(
    const ushort* __restrict__ h, const float* __restrict__ W,
    ushort* __restrict__ out, int n) {
  __shared__ ushort Wt[OD * 128];   // [col][k] bf16, swizzled
  const int tid = threadIdx.x;
  for (int idx = tid; idx < 128 * OD; idx += TPB) {
    int k = idx / OD, c = idx - k * OD;
    Wt[c * 128 + (k ^ ((c & 7) << 3))] = f2bf(W[idx]);
  }
  __syncthreads();
  const int lane = tid & 63, wave = tid >> 6;
  const int rowA = lane & 15, kgrp = lane >> 4;
  const int nb0 = blockIdx.x * 64 + wave * 16;
  int nodeA = nb0 + rowA; if (nodeA >= n) nodeA = n - 1;
  const ushort* hrow = h + (size_t)nodeA * 128 + kgrp * 8;
  short8v a0 = *(const short8v*)(hrow);
  short8v a1 = *(const short8v*)(hrow + 32);
  short8v a2 = *(const short8v*)(hrow + 64);
  short8v a3 = *(const short8v*)(hrow + 96);
  #pragma unroll
  for (int ct = 0; ct < OD / 16; ++ct) {
    const int c = ct * 16 + rowA;
    const int sw = (c & 7) << 3;
    const ushort* wc = &Wt[c * 128];
    float4v acc = {0.f, 0.f, 0.f, 0.f};
    acc = __builtin_amdgcn_mfma_f32_16x16x32_bf16(a0, *(const short8v*)(wc + ((kgrp * 8)       ^ sw)), acc, 0, 0, 0);
    acc = __builtin_amdgcn_mfma_f32_16x16x32_bf16(a1, *(const short8v*)(wc + ((kgrp * 8 + 32)  ^ sw)), acc, 0, 0, 0);
    acc = __builtin_amdgcn_mfma_f32_16x16x32_bf16(a2, *(const short8v*)(wc + ((kgrp * 8 + 64)  ^ sw)), acc, 0, 0, 0);
    acc = __builtin_amdgcn_mfma_f32_16x16x32_bf16(a3, *(const short8v*)(wc + ((kgrp * 8 + 96)  ^ sw)), acc, 0, 0, 0);
    #pragma unroll
    for (int r = 0; r < 4; ++r) {
      int node = nb0 + kgrp * 4 + r;
      if (node < n) out[(size_t)node * OD + c] = f2bf(acc[r]);
    }
  }
}

// ------- quant: bf16 rows -> biased int8 rows + scale, sdinv = scale*dinv -------
template <int OD>
__global__ __launch_bounds__(256) void quant_kernel(
    const ushort* __restrict__ hlin, unsigned char* __restrict__ q,
    float* __restrict__ scale, float* __restrict__ sdinv,
    const float* __restrict__ dinv, int n) {
  constexpr int CPL = OD / 16;                 // cols per lane: 8 or 4
  const int tid = threadIdx.x;
  const int grp = tid >> 4, L = tid & 15;
  for (int row = blockIdx.x * 16 + grp; row < n; row += gridDim.x * 16) {
    const ushort* hr = hlin + (size_t)row * OD + CPL * L;
    float v[CPL];
    #pragma unroll
    for (int c = 0; c < CPL; ++c) v[c] = bf2f(hr[c]);
    float m = 0.f;
    #pragma unroll
    for (int c = 0; c < CPL; ++c) m = fmaxf(m, fabsf(v[c]));
    #pragma unroll
    for (int o = 1; o < 16; o <<= 1) m = fmaxf(m, __shfl_xor(m, o, 16));
    float inv = (m > 0.f) ? 127.f / m : 0.f;
    unsigned int pk[CPL / 4];
    #pragma unroll
    for (int wq = 0; wq < CPL / 4; ++wq) {
      unsigned int p = 0;
      #pragma unroll
      for (int c = 0; c < 4; ++c) {
        int qv = (int)rintf(v[wq * 4 + c] * inv) + 128;
        p |= ((unsigned int)(qv & 255)) << (8 * c);
      }
      pk[wq] = p;
    }
    unsigned char* qr = q + (size_t)row * OD + CPL * L;
    if (CPL == 8) *(uint2*)qr = make_uint2(pk[0], pk[CPL / 4 - 1]);
    else          *(unsigned int*)qr = pk[0];
    if (L == 0) {
      float sc = m * (1.f / 127.f);
      scale[row] = sc;
      sdinv[row] = sc * dinv[row];
    }
  }
}

// ---------------- CSR build (XCD-replicated histogram) ----------------
__global__ void deg_rank_kernel(const int* __restrict__ dst, int* __restrict__ cnt8,
                                int* __restrict__ rank, int n, int e) {
  int i = blockIdx.x * TPB + threadIdx.x;
  int r = blockIdx.x & (NR - 1);
  if (i < e) rank[i] = atomicAdd(&cnt8[(size_t)r * n + dst[i]], 1);
}

// fold replicas: deg, dinv, in-place replica exclusive offsets, block-scan of deg
__global__ void scan1_kernel(int* __restrict__ cnt8, int* __restrict__ rowptr,
                             int* __restrict__ bsum, float* __restrict__ dinv, int n) {
  __shared__ int sh[TPB];
  int i = blockIdx.x * TPB + threadIdx.x;
  int deg = 0;
  if (i < n) {
    int c[NR];
    #pragma unroll
    for (int r = 0; r < NR; ++r) { c[r] = cnt8[(size_t)r * n + i]; deg += c[r]; }
    int acc = 0;
    #pragma unroll
    for (int r = 0; r < NR; ++r) { int t = c[r]; cnt8[(size_t)r * n + i] = acc; acc += t; }
    dinv[i] = rsqrtf((float)deg + 1.f);
  }
  sh[threadIdx.x] = deg;
  __syncthreads();
  for (int off = 1; off < TPB; off <<= 1) {
    int t = (threadIdx.x >= off) ? sh[threadIdx.x - off] : 0;
    __syncthreads();
    sh[threadIdx.x] += t;
    __syncthreads();
  }
  if (i < n) rowptr[i] = sh[threadIdx.x] - deg;
  if (threadIdx.x == TPB - 1) bsum[blockIdx.x] = sh[threadIdx.x];
}

__global__ void scan2_kernel(int* __restrict__ bsum, int nb) {
  __shared__ int sh[512];
  __shared__ int carry;
  if (threadIdx.x == 0) carry = 0;
  __syncthreads();
  for (int base = 0; base < nb; base += 512) {
    int i = base + threadIdx.x;
    int v = (i < nb) ? bsum[i] : 0;
    sh[threadIdx.x] = v;
    __syncthreads();
    for (int off = 1; off < 512; off <<= 1) {
      int t = (threadIdx.x >= off) ? sh[threadIdx.x - off] : 0;
      __syncthreads();
      sh[threadIdx.x] += t;
      __syncthreads();
    }
    if (i < nb) bsum[i] = carry + sh[threadIdx.x] - v;
    __syncthreads();
    if (threadIdx.x == 0) carry += sh[511];
    __syncthreads();
  }
}

// finalize rowptr; emit per-replica row pointers rptr8[r][i] = rowptr[i]+repoff[r][i]
__global__ void scan3_kernel(int* __restrict__ rowptr, const int* __restrict__ bsum,
                             const int* __restrict__ cnt8, int* __restrict__ rptr8,
                             int n, int e) {
  int i = blockIdx.x * TPB + threadIdx.x;
  if (i < n) {
    int rp = rowptr[i] + bsum[blockIdx.x];
    rowptr[i] = rp;
    #pragma unroll
    for (int r = 0; r < NR; ++r)
      rptr8[(size_t)r * n + i] = rp + cnt8[(size_t)r * n + i];
  }
  if (i == 0) rowptr[n] = e;
}

// place via XCD-local rptr8 slab + gstart fused
__global__ void place_kernel(const int* __restrict__ src, const int* __restrict__ dst,
                             const int* __restrict__ rptr8, const int* __restrict__ rank,
                             int* __restrict__ csr_src,
                             const int* __restrict__ batch, int* __restrict__ gstart,
                             int n, int G, int e) {
  int i = blockIdx.x * TPB + threadIdx.x;
  if (i < e) {
    int r = (i >> 8) & (NR - 1);          // must match deg_rank's block->replica map
    csr_src[rptr8[(size_t)r * n + dst[i]] + rank[i]] = src[i];
  }
  if (i < n) {
    int bi = batch[i];
    int bp = (i == 0) ? -1 : batch[i - 1];
    for (int g = bp + 1; g <= bi; ++g) gstart[g] = i;
    if (i == n - 1)
      for (int g = bi + 1; g <= G; ++g) gstart[g] = n;
  }
}

// --- gather int8 rows (biased +128), fused finalize, bf16 out ---
template <int OD>
__global__ __launch_bounds__(256) void gather_i8_kernel(
    const unsigned char* __restrict__ q, const float* __restrict__ scale,
    const float* __restrict__ sdinv, const int* __restrict__ rowptr,
    const int* __restrict__ csr_src, const float* __restrict__ dinv,
    const float* __restrict__ b, ushort* __restrict__ out, int n) {
  constexpr int Q8 = OD / 8;                    // threads per node (16 or 8)
  constexpr int NS = TPB / Q8;
  const int tid = threadIdx.x;
  const int tx = tid & (Q8 - 1), slot = tid / Q8;
  int node = blockIdx.x * NS + slot;
  if (node >= n) return;
  const uint2* qrow = (const uint2*)q;
  int start = rowptr[node], end = rowptr[node + 1];
  float di = dinv[node];
  float acc[8];
  #pragma unroll
  for (int c = 0; c < 8; ++c) acc[c] = 0.f;
  float wsum = 0.f;
  int j = start;
  for (; j + 3 < end; j += 4) {
    int s[4]; uint2 v[4]; float w[4];
    #pragma unroll
    for (int u = 0; u < 4; ++u) s[u] = csr_src[j + u];
    #pragma unroll
    for (int u = 0; u < 4; ++u) v[u] = qrow[(size_t)s[u] * Q8 + tx];
    #pragma unroll
    for (int u = 0; u < 4; ++u) w[u] = sdinv[s[u]] * di;
    #pragma unroll
    for (int u = 0; u < 4; ++u) {
      wsum += w[u];
      acc[0] += w[u] * (float)( v[u].x        & 255u);
      acc[1] += w[u] * (float)((v[u].x >>  8) & 255u);
      acc[2] += w[u] * (float)((v[u].x >> 16) & 255u);
      acc[3] += w[u] * (float)( v[u].x >> 24);
      acc[4] += w[u] * (float)( v[u].y        & 255u);
      acc[5] += w[u] * (float)((v[u].y >>  8) & 255u);
      acc[6] += w[u] * (float)((v[u].y >> 16) & 255u);
      acc[7] += w[u] * (float)( v[u].y >> 24);
    }
  }
  for (; j < end; ++j) {
    int s0 = csr_src[j];
    uint2 v0 = qrow[(size_t)s0 * Q8 + tx];
    float w0 = sdinv[s0] * di;
    wsum += w0;
    acc[0] += w0 * (float)( v0.x        & 255u);
    acc[1] += w0 * (float)((v0.x >>  8) & 255u);
    acc[2] += w0 * (float)((v0.x >> 16) & 255u);
    acc[3] += w0 * (float)( v0.x >> 24);
    acc[4] += w0 * (float)( v0.y        & 255u);
    acc[5] += w0 * (float)((v0.y >>  8) & 255u);
    acc[6] += w0 * (float)((v0.y >> 16) & 255u);
    acc[7] += w0 * (float)( v0.y >> 24);
  }
  uint2 sv = qrow[(size_t)node * Q8 + tx];
  float ss = scale[node] * di * di;
  float su[8];
  su[0] = (float)( sv.x        & 255u); su[1] = (float)((sv.x >>  8) & 255u);
  su[2] = (float)((sv.x >> 16) & 255u); su[3] = (float)( sv.x >> 24);
  su[4] = (float)( sv.y        & 255u); su[5] = (float)((sv.y >>  8) & 255u);
  su[6] = (float)((sv.y >> 16) & 255u); su[7] = (float)( sv.y >> 24);
  float4 b0 = *(const float4*)(b + 8 * tx);
  float4 b1 = *(const float4*)(b + 8 * tx + 4);
  float bb[8] = {b0.x, b0.y, b0.z, b0.w, b1.x, b1.y, b1.z, b1.w};
  short8v o;
  #pragma unroll
  for (int c = 0; c < 8; ++c) {
    float val = acc[c] - 128.f * wsum + ss * (su[c] - 128.f) + bb[c];
    o[c] = (short)f2bf(fmaxf(val, 0.f));
  }
  *(short8v*)(out + (size_t)node * OD + 8 * tx) = o;
}

// ---------------- pool: batch sorted -> segment mean (bf16 in, fp32 out) ----------------
__global__ __launch_bounds__(256) void pool2_kernel(
    const ushort* __restrict__ h, const int* __restrict__ gstart,
    float* __restrict__ out) {
  __shared__ float sh[4][LAT];
  int g = blockIdx.x;
  int s = gstart[g], epos = gstart[g + 1];
  int c = threadIdx.x & (LAT - 1), r = threadIdx.x >> 6;
  float acc = 0.f;
  for (int i = s + r; i < epos; i += 4)
    acc += bf2f(h[(size_t)i * LAT + c]);
  sh[r][c] = acc;
  __syncthreads();
  if (r == 0) {
    float v = sh[0][c] + sh[1][c] + sh[2][c] + sh[3][c];
    out[(size_t)g * LAT + c] = v / fmaxf((float)(epos - s), 1.f);
  }
}

extern "C" void kernel_launch(void* const* d_in, const int* in_sizes, int n_in,
                              void* d_out, int out_size, void* d_ws, size_t ws_size,
                              hipStream_t stream) {
  const float* x     = (const float*)d_in[0];
  const float* W_emb = (const float*)d_in[1];
  const float* b_emb = (const float*)d_in[2];
  const float* W1    = (const float*)d_in[3];
  const float* b1    = (const float*)d_in[4];
  const float* W2    = (const float*)d_in[5];
  const float* b2    = (const float*)d_in[6];
  const int*   ei    = (const int*)d_in[7];
  const int*   batch = (const int*)d_in[8];
  const int n = in_sizes[8];
  const int e = in_sizes[7] / 2;
  const int* srcp = ei;
  const int* dstp = ei + e;
  float* out = (float*)d_out;

  char* ws = (char*)d_ws;
  size_t off = 0;
  auto alloc = [&](size_t bytes) {
    void* p = ws + off;
    off += (bytes + 255) & ~(size_t)255;
    return p;
  };
  ushort* bufA    = (ushort*)alloc((size_t)n * HID * 2);        // h0/h1/h2 bf16
  ushort* bufB    = (ushort*)alloc((size_t)n * HID * 2);        // hlin bf16
  unsigned char* bufQ = (unsigned char*)alloc((size_t)n * HID); // int8 rows
  float*  scaleq  = (float*)alloc((size_t)n * 4);
  float*  sdinv   = (float*)alloc((size_t)n * 4);
  float*  dinv    = (float*)alloc((size_t)n * 4);
  int*    cnt8    = (int*)alloc((size_t)NR * n * 4);            // replicated hist / repoff
  int*    rptr8   = (int*)alloc((size_t)NR * n * 4);            // per-replica row ptrs
  int*    rowptr  = (int*)alloc((size_t)(n + 1) * 4);
  int*    bsum    = (int*)alloc((size_t)512 * 4);
  int*    rank    = (int*)alloc((size_t)e * 4);
  int*    csr_src = (int*)alloc((size_t)e * 4);
  int*    gstart  = (int*)alloc((size_t)(GG + 1) * 4);

  const int nb = (n + TPB - 1) / TPB;
  const int eb = (e + TPB - 1) / TPB;
  const int mb = (n + 63) / 64;

  // h0 = relu(x @ W_emb + b_emb) -> bufA ; zero cnt8
  embed_kernel<<<2048, TPB, 0, stream>>>(x, W_emb, b_emb, bufA, cnt8, n);

  // CSR by dst, XCD-replicated counting
  deg_rank_kernel<<<eb, TPB, 0, stream>>>(dstp, cnt8, rank, n, e);
  scan1_kernel<<<nb, TPB, 0, stream>>>(cnt8, rowptr, bsum, dinv, n);
  scan2_kernel<<<1, 512, 0, stream>>>(bsum, nb);
  scan3_kernel<<<nb, TPB, 0, stream>>>(rowptr, bsum, cnt8, rptr8, n, e);
  place_kernel<<<eb, TPB, 0, stream>>>(srcp, dstp, rptr8, rank, csr_src,
                                       batch, gstart, n, GG, e);

  // conv1: lin -> bufB; quant -> bufQ; gather(int8) -> bufA
  lin_mfma_kernel<HID><<<mb, TPB, 0, stream>>>(bufA, W1, bufB, n);
  quant_kernel<HID><<<2048, TPB, 0, stream>>>(bufB, bufQ, scaleq, sdinv, dinv, n);
  gather_i8_kernel<HID><<<(n * (HID / 8) + TPB - 1) / TPB, TPB, 0, stream>>>(
      bufQ, scaleq, sdinv, rowptr, csr_src, dinv, b1, bufA, n);

  // conv2: lin -> bufB (n x 64); quant; gather(int8) -> bufA (n x 64)
  lin_mfma_kernel<LAT><<<mb, TPB, 0, stream>>>(bufA, W2, bufB, n);
  quant_kernel<LAT><<<2048, TPB, 0, stream>>>(bufB, bufQ, scaleq, sdinv, dinv, n);
  gather_i8_kernel<LAT><<<(n * (LAT / 8) + TPB - 1) / TPB, TPB, 0, stream>>>(
      bufQ, scaleq, sdinv, rowptr, csr_src, dinv, b2, bufA, n);

  // mean pool
  pool2_kernel<<<GG, TPB, 0, stream>>>(bufA, gstart, out);
}

// Round 10
// 212.620 us; speedup vs baseline: 1.3936x; 1.2385x over previous
//
#include <hip/hip_runtime.h>

#define TPB 256
constexpr int DIN = 47;
constexpr int HID = 128;
constexpr int LAT = 64;
constexpr int GG  = 1024;
constexpr int NBMAX = 512;   // max dst-buckets (256 nodes each)
constexpr int PB  = 256;     // partition blocks

typedef __attribute__((ext_vector_type(8))) short short8v;
typedef __attribute__((ext_vector_type(4))) float float4v;

__device__ inline ushort f2bf(float f) {          // round-to-nearest-even bf16
  uint32_t u = __float_as_uint(f);
  return (ushort)((u + 0x7FFFu + ((u >> 16) & 1u)) >> 16);
}
__device__ inline float bf2f(ushort s) {
  return __uint_as_float(((uint32_t)s) << 16);
}

// ---------------- embed: out(bf16) = relu(x @ W_emb + b) ----------------
__global__ __launch_bounds__(256) void embed_kernel(
    const float* __restrict__ x, const float* __restrict__ W,
    const float* __restrict__ b, ushort* __restrict__ out, int n) {
  __shared__ float Wl[DIN * HID];
  __shared__ float bl[HID];
  __shared__ float xs[8][48];
  const int tid = threadIdx.x;
  for (int i = tid; i < DIN * HID; i += TPB) Wl[i] = W[i];
  if (tid < HID) bl[tid] = b[tid];
  const int tx = tid & 31, slot = tid >> 5;
  const float4* Wl4 = (const float4*)Wl;
  for (int base = blockIdx.x * 8; base < n; base += gridDim.x * 8) {
    __syncthreads();
    for (int i = tid; i < 8 * DIN; i += TPB) {
      int s = i / DIN, k = i - s * DIN;
      int node = base + s;
      xs[s][k] = (node < n) ? x[node * DIN + k] : 0.f;
    }
    __syncthreads();
    int node = base + slot;
    if (node < n) {
      float4 acc = ((const float4*)bl)[tx];
      #pragma unroll
      for (int k = 0; k < DIN; ++k) {
        float xv = xs[slot][k];
        float4 w = Wl4[k * 32 + tx];
        acc.x += xv * w.x; acc.y += xv * w.y; acc.z += xv * w.z; acc.w += xv * w.w;
      }
      ushort4 o;
      o.x = f2bf(fmaxf(acc.x, 0.f)); o.y = f2bf(fmaxf(acc.y, 0.f));
      o.z = f2bf(fmaxf(acc.z, 0.f)); o.w = f2bf(fmaxf(acc.w, 0.f));
      ((ushort4*)out)[node * 32 + tx] = o;
    }
  }
}

// ------- lin (MFMA): out[n,OD] bf16 = h[n,128] bf16 @ W[128,OD] fp32->bf16 -------
template <int OD>
__global__ __launch_bounds__(256) void lin_mfma_kernel(
    const ushort* __restrict__ h, const float* __restrict__ W,
    ushort* __restrict__ out, int n) {
  __shared__ ushort Wt[OD * 128];   // [col][k] bf16, swizzled
  const int tid = threadIdx.x;
  for (int idx = tid; idx < 128 * OD; idx += TPB) {
    int k = idx / OD, c = idx - k * OD;
    Wt[c * 128 + (k ^ ((c & 7) << 3))] = f2bf(W[idx]);
  }
  __syncthreads();
  const int lane = tid & 63, wave = tid >> 6;
  const int rowA = lane & 15, kgrp = lane >> 4;
  const int nb0 = blockIdx.x * 64 + wave * 16;
  int nodeA = nb0 + rowA; if (nodeA >= n) nodeA = n - 1;
  const ushort* hrow = h + (size_t)nodeA * 128 + kgrp * 8;
  short8v a0 = *(const short8v*)(hrow);
  short8v a1 = *(const short8v*)(hrow + 32);
  short8v a2 = *(const short8v*)(hrow + 64);
  short8v a3 = *(const short8v*)(hrow + 96);
  #pragma unroll
  for (int ct = 0; ct < OD / 16; ++ct) {
    const int c = ct * 16 + rowA;
    const int sw = (c & 7) << 3;
    const ushort* wc = &Wt[c * 128];
    float4v acc = {0.f, 0.f, 0.f, 0.f};
    acc = __builtin_amdgcn_mfma_f32_16x16x32_bf16(a0, *(const short8v*)(wc + ((kgrp * 8)       ^ sw)), acc, 0, 0, 0);
    acc = __builtin_amdgcn_mfma_f32_16x16x32_bf16(a1, *(const short8v*)(wc + ((kgrp * 8 + 32)  ^ sw)), acc, 0, 0, 0);
    acc = __builtin_amdgcn_mfma_f32_16x16x32_bf16(a2, *(const short8v*)(wc + ((kgrp * 8 + 64)  ^ sw)), acc, 0, 0, 0);
    acc = __builtin_amdgcn_mfma_f32_16x16x32_bf16(a3, *(const short8v*)(wc + ((kgrp * 8 + 96)  ^ sw)), acc, 0, 0, 0);
    #pragma unroll
    for (int r = 0; r < 4; ++r) {
      int node = nb0 + kgrp * 4 + r;
      if (node < n) out[(size_t)node * OD + c] = f2bf(acc[r]);
    }
  }
}

// ------- quant: bf16 rows -> biased int8 rows + scale, sdinv = scale*dinv -------
template <int OD>
__global__ __launch_bounds__(256) void quant_kernel(
    const ushort* __restrict__ hlin, unsigned char* __restrict__ q,
    float* __restrict__ scale, float* __restrict__ sdinv,
    const float* __restrict__ dinv, int n) {
  constexpr int CPL = OD / 16;                 // cols per lane: 8 or 4
  const int tid = threadIdx.x;
  const int grp = tid >> 4, L = tid & 15;
  for (int row = blockIdx.x * 16 + grp; row < n; row += gridDim.x * 16) {
    const ushort* hr = hlin + (size_t)row * OD + CPL * L;
    float v[CPL];
    #pragma unroll
    for (int c = 0; c < CPL; ++c) v[c] = bf2f(hr[c]);
    float m = 0.f;
    #pragma unroll
    for (int c = 0; c < CPL; ++c) m = fmaxf(m, fabsf(v[c]));
    #pragma unroll
    for (int o = 1; o < 16; o <<= 1) m = fmaxf(m, __shfl_xor(m, o, 16));
    float inv = (m > 0.f) ? 127.f / m : 0.f;
    unsigned int pk[CPL / 4];
    #pragma unroll
    for (int wq = 0; wq < CPL / 4; ++wq) {
      unsigned int p = 0;
      #pragma unroll
      for (int c = 0; c < 4; ++c) {
        int qv = (int)rintf(v[wq * 4 + c] * inv) + 128;
        p |= ((unsigned int)(qv & 255)) << (8 * c);
      }
      pk[wq] = p;
    }
    unsigned char* qr = q + (size_t)row * OD + CPL * L;
    if (CPL == 8) *(uint2*)qr = make_uint2(pk[0], pk[CPL / 4 - 1]);
    else          *(unsigned int*)qr = pk[0];
    if (L == 0) {
      float sc = m * (1.f / 127.f);
      scale[row] = sc;
      sdinv[row] = sc * dinv[row];
    }
  }
}

// ---------------- CSR build: two-level LDS counting sort (no global atomics) ----------------
// stage 1: per-block bucket histogram (bucket = dst>>8)
__global__ __launch_bounds__(256) void histA_kernel(
    const int* __restrict__ dst, int* __restrict__ blockhist, int e, int nbuck) {
  __shared__ int hist[NBMAX];
  const int tid = threadIdx.x;
  for (int i = tid; i < nbuck; i += TPB) hist[i] = 0;
  __syncthreads();
  const int per = (e + PB - 1) / PB;
  const int lo = blockIdx.x * per;
  const int hi = min(lo + per, e);
  for (int i = lo + tid; i < hi; i += TPB)
    atomicAdd(&hist[dst[i] >> 8], 1);                 // LDS atomic
  __syncthreads();
  for (int i = tid; i < nbuck; i += TPB)
    blockhist[(size_t)i * PB + blockIdx.x] = hist[i]; // bucket-major
}

// generic exclusive scan over m ints, in place (3 kernels)
__global__ void scanG1_kernel(int* __restrict__ a, int* __restrict__ bsum, int m) {
  __shared__ int sh[TPB];
  int i = blockIdx.x * TPB + threadIdx.x;
  int v = (i < m) ? a[i] : 0;
  sh[threadIdx.x] = v;
  __syncthreads();
  for (int off = 1; off < TPB; off <<= 1) {
    int t = (threadIdx.x >= off) ? sh[threadIdx.x - off] : 0;
    __syncthreads();
    sh[threadIdx.x] += t;
    __syncthreads();
  }
  if (i < m) a[i] = sh[threadIdx.x] - v;
  if (threadIdx.x == TPB - 1) bsum[blockIdx.x] = sh[threadIdx.x];
}

__global__ void scan2_kernel(int* __restrict__ bsum, int nb) {
  __shared__ int sh[512];
  __shared__ int carry;
  if (threadIdx.x == 0) carry = 0;
  __syncthreads();
  for (int base = 0; base < nb; base += 512) {
    int i = base + threadIdx.x;
    int v = (i < nb) ? bsum[i] : 0;
    sh[threadIdx.x] = v;
    __syncthreads();
    for (int off = 1; off < 512; off <<= 1) {
      int t = (threadIdx.x >= off) ? sh[threadIdx.x - off] : 0;
      __syncthreads();
      sh[threadIdx.x] += t;
      __syncthreads();
    }
    if (i < nb) bsum[i] = carry + sh[threadIdx.x] - v;
    __syncthreads();
    if (threadIdx.x == 0) carry += sh[511];
    __syncthreads();
  }
}

__global__ void scanG3_kernel(int* __restrict__ a, const int* __restrict__ bsum, int m) {
  int i = blockIdx.x * TPB + threadIdx.x;
  if (i < m) a[i] += bsum[blockIdx.x];
}

// stage 2: scatter edges into bucket segments (packed src,dst); gstart fused
__global__ __launch_bounds__(256) void scatterA_kernel(
    const int* __restrict__ src, const int* __restrict__ dst,
    const int* __restrict__ off, uint2* __restrict__ ppack, int e, int nbuck,
    const int* __restrict__ batch, int* __restrict__ gstart, int n, int G) {
  __shared__ int ofs[NBMAX];
  const int tid = threadIdx.x;
  for (int i = tid; i < nbuck; i += TPB)
    ofs[i] = off[(size_t)i * PB + blockIdx.x];
  __syncthreads();
  const int per = (e + PB - 1) / PB;
  const int lo = blockIdx.x * per;
  const int hi = min(lo + per, e);
  for (int i = lo + tid; i < hi; i += TPB) {
    int s = src[i], d = dst[i];
    int p = atomicAdd(&ofs[d >> 8], 1);               // LDS atomic
    ppack[p] = make_uint2((unsigned)s, (unsigned)d);
  }
  // gstart (batch sorted)
  for (int i = blockIdx.x * TPB + tid; i < n; i += PB * TPB) {
    int bi = batch[i];
    int bp = (i == 0) ? -1 : batch[i - 1];
    for (int g = bp + 1; g <= bi; ++g) gstart[g] = i;
    if (i == n - 1)
      for (int g = bi + 1; g <= G; ++g) gstart[g] = n;
  }
}

// stage 3: per-bucket counting sort -> rowptr, dinv, csr_src
__global__ __launch_bounds__(256) void bucketB_kernel(
    const uint2* __restrict__ ppack, const int* __restrict__ off,
    int* __restrict__ rowptr, float* __restrict__ dinv, int* __restrict__ csr_src,
    int n, int e, int nbuck) {
  __shared__ int cnt[256];
  __shared__ int sh[256];
  const int tid = threadIdx.x;
  const int b = blockIdx.x;
  const int bs = off[(size_t)b * PB];
  const int be = (b + 1 < nbuck) ? off[(size_t)(b + 1) * PB] : e;
  cnt[tid] = 0;
  __syncthreads();
  for (int i = bs + tid; i < be; i += TPB)
    atomicAdd(&cnt[ppack[i].y & 255], 1);             // LDS atomic
  __syncthreads();
  const int deg = cnt[tid];
  sh[tid] = deg;
  __syncthreads();
  for (int o = 1; o < 256; o <<= 1) {
    int t = (tid >= o) ? sh[tid - o] : 0;
    __syncthreads();
    sh[tid] += t;
    __syncthreads();
  }
  const int loff = sh[tid] - deg;                     // exclusive within bucket
  const int node = b * 256 + tid;
  if (node < n) {
    rowptr[node] = bs + loff;
    dinv[node] = rsqrtf((float)deg + 1.f);
  }
  if (b == nbuck - 1 && tid == TPB - 1) rowptr[n] = e;
  cnt[tid] = loff;                                    // running cursor
  __syncthreads();
  for (int i = bs + tid; i < be; i += TPB) {
    uint2 p = ppack[i];
    int pos = atomicAdd(&cnt[p.y & 255], 1);          // LDS atomic
    csr_src[bs + pos] = (int)p.x;
  }
}

// --- gather int8 rows (biased +128), fused finalize, bf16 out ---
template <int OD>
__global__ __launch_bounds__(256) void gather_i8_kernel(
    const unsigned char* __restrict__ q, const float* __restrict__ scale,
    const float* __restrict__ sdinv, const int* __restrict__ rowptr,
    const int* __restrict__ csr_src, const float* __restrict__ dinv,
    const float* __restrict__ b, ushort* __restrict__ out, int n) {
  constexpr int Q8 = OD / 8;                    // threads per node (16 or 8)
  constexpr int NS = TPB / Q8;
  const int tid = threadIdx.x;
  const int tx = tid & (Q8 - 1), slot = tid / Q8;
  int node = blockIdx.x * NS + slot;
  if (node >= n) return;
  const uint2* qrow = (const uint2*)q;
  int start = rowptr[node], end = rowptr[node + 1];
  float di = dinv[node];
  float acc[8];
  #pragma unroll
  for (int c = 0; c < 8; ++c) acc[c] = 0.f;
  float wsum = 0.f;
  int j = start;
  for (; j + 3 < end; j += 4) {
    int s[4]; uint2 v[4]; float w[4];
    #pragma unroll
    for (int u = 0; u < 4; ++u) s[u] = csr_src[j + u];
    #pragma unroll
    for (int u = 0; u < 4; ++u) v[u] = qrow[(size_t)s[u] * Q8 + tx];
    #pragma unroll
    for (int u = 0; u < 4; ++u) w[u] = sdinv[s[u]] * di;
    #pragma unroll
    for (int u = 0; u < 4; ++u) {
      wsum += w[u];
      acc[0] += w[u] * (float)( v[u].x        & 255u);
      acc[1] += w[u] * (float)((v[u].x >>  8) & 255u);
      acc[2] += w[u] * (float)((v[u].x >> 16) & 255u);
      acc[3] += w[u] * (float)( v[u].x >> 24);
      acc[4] += w[u] * (float)( v[u].y        & 255u);
      acc[5] += w[u] * (float)((v[u].y >>  8) & 255u);
      acc[6] += w[u] * (float)((v[u].y >> 16) & 255u);
      acc[7] += w[u] * (float)( v[u].y >> 24);
    }
  }
  for (; j < end; ++j) {
    int s0 = csr_src[j];
    uint2 v0 = qrow[(size_t)s0 * Q8 + tx];
    float w0 = sdinv[s0] * di;
    wsum += w0;
    acc[0] += w0 * (float)( v0.x        & 255u);
    acc[1] += w0 * (float)((v0.x >>  8) & 255u);
    acc[2] += w0 * (float)((v0.x >> 16) & 255u);
    acc[3] += w0 * (float)( v0.x >> 24);
    acc[4] += w0 * (float)( v0.y        & 255u);
    acc[5] += w0 * (float)((v0.y >>  8) & 255u);
    acc[6] += w0 * (float)((v0.y >> 16) & 255u);
    acc[7] += w0 * (float)( v0.y >> 24);
  }
  uint2 sv = qrow[(size_t)node * Q8 + tx];
  float ss = scale[node] * di * di;
  float su[8];
  su[0] = (float)( sv.x        & 255u); su[1] = (float)((sv.x >>  8) & 255u);
  su[2] = (float)((sv.x >> 16) & 255u); su[3] = (float)( sv.x >> 24);
  su[4] = (float)( sv.y        & 255u); su[5] = (float)((sv.y >>  8) & 255u);
  su[6] = (float)((sv.y >> 16) & 255u); su[7] = (float)( sv.y >> 24);
  float4 b0 = *(const float4*)(b + 8 * tx);
  float4 b1 = *(const float4*)(b + 8 * tx + 4);
  float bb[8] = {b0.x, b0.y, b0.z, b0.w, b1.x, b1.y, b1.z, b1.w};
  short8v o;
  #pragma unroll
  for (int c = 0; c < 8; ++c) {
    float val = acc[c] - 128.f * wsum + ss * (su[c] - 128.f) + bb[c];
    o[c] = (short)f2bf(fmaxf(val, 0.f));
  }
  *(short8v*)(out + (size_t)node * OD + 8 * tx) = o;
}

// ---------------- pool: batch sorted -> segment mean (bf16 in, fp32 out) ----------------
__global__ __launch_bounds__(256) void pool2_kernel(
    const ushort* __restrict__ h, const int* __restrict__ gstart,
    float* __restrict__ out) {
  __shared__ float sh[4][LAT];
  int g = blockIdx.x;
  int s = gstart[g], epos = gstart[g + 1];
  int c = threadIdx.x & (LAT - 1), r = threadIdx.x >> 6;
  float acc = 0.f;
  for (int i = s + r; i < epos; i += 4)
    acc += bf2f(h[(size_t)i * LAT + c]);
  sh[r][c] = acc;
  __syncthreads();
  if (r == 0) {
    float v = sh[0][c] + sh[1][c] + sh[2][c] + sh[3][c];
    out[(size_t)g * LAT + c] = v / fmaxf((float)(epos - s), 1.f);
  }
}

extern "C" void kernel_launch(void* const* d_in, const int* in_sizes, int n_in,
                              void* d_out, int out_size, void* d_ws, size_t ws_size,
                              hipStream_t stream) {
  const float* x     = (const float*)d_in[0];
  const float* W_emb = (const float*)d_in[1];
  const float* b_emb = (const float*)d_in[2];
  const float* W1    = (const float*)d_in[3];
  const float* b1    = (const float*)d_in[4];
  const float* W2    = (const float*)d_in[5];
  const float* b2    = (const float*)d_in[6];
  const int*   ei    = (const int*)d_in[7];
  const int*   batch = (const int*)d_in[8];
  const int n = in_sizes[8];
  const int e = in_sizes[7] / 2;
  const int* srcp = ei;
  const int* dstp = ei + e;
  float* out = (float*)d_out;

  char* ws = (char*)d_ws;
  size_t off_ = 0;
  auto alloc = [&](size_t bytes) {
    void* p = ws + off_;
    off_ += (bytes + 255) & ~(size_t)255;
    return p;
  };
  ushort* bufA    = (ushort*)alloc((size_t)n * HID * 2);        // h0/h1/h2 bf16
  ushort* bufB    = (ushort*)alloc((size_t)n * HID * 2);        // hlin bf16
  unsigned char* bufQ = (unsigned char*)alloc((size_t)n * HID); // int8 rows
  float*  scaleq  = (float*)alloc((size_t)n * 4);
  float*  sdinv   = (float*)alloc((size_t)n * 4);
  float*  dinv    = (float*)alloc((size_t)n * 4);
  int*    blockhist = (int*)alloc((size_t)NBMAX * PB * 4);      // bucket-major hist -> offsets
  int*    rowptr  = (int*)alloc((size_t)(n + 1) * 4);
  int*    bsum    = (int*)alloc((size_t)512 * 4);
  uint2*  ppack   = (uint2*)alloc((size_t)e * 8);               // partitioned (src,dst)
  int*    csr_src = (int*)alloc((size_t)e * 4);
  int*    gstart  = (int*)alloc((size_t)(GG + 1) * 4);

  const int nbuck = (n + 255) / 256;                 // 391
  const int m = nbuck * PB;                          // scan length
  const int mb2 = (m + TPB - 1) / TPB;
  const int mb = (n + 63) / 64;

  // h0 = relu(x @ W_emb + b_emb) -> bufA
  embed_kernel<<<2048, TPB, 0, stream>>>(x, W_emb, b_emb, bufA, n);

  // CSR build: hist -> scan -> scatter -> per-bucket sort (LDS atomics only)
  histA_kernel<<<PB, TPB, 0, stream>>>(dstp, blockhist, e, nbuck);
  scanG1_kernel<<<mb2, TPB, 0, stream>>>(blockhist, bsum, m);
  scan2_kernel<<<1, 512, 0, stream>>>(bsum, mb2);
  scanG3_kernel<<<mb2, TPB, 0, stream>>>(blockhist, bsum, m);
  scatterA_kernel<<<PB, TPB, 0, stream>>>(srcp, dstp, blockhist, ppack, e, nbuck,
                                          batch, gstart, n, GG);
  bucketB_kernel<<<nbuck, TPB, 0, stream>>>(ppack, blockhist, rowptr, dinv, csr_src,
                                            n, e, nbuck);

  // conv1: lin -> bufB; quant -> bufQ; gather(int8) -> bufA
  lin_mfma_kernel<HID><<<mb, TPB, 0, stream>>>(bufA, W1, bufB, n);
  quant_kernel<HID><<<2048, TPB, 0, stream>>>(bufB, bufQ, scaleq, sdinv, dinv, n);
  gather_i8_kernel<HID><<<(n * (HID / 8) + TPB - 1) / TPB, TPB, 0, stream>>>(
      bufQ, scaleq, sdinv, rowptr, csr_src, dinv, b1, bufA, n);

  // conv2: lin -> bufB (n x 64); quant; gather(int8) -> bufA (n x 64)
  lin_mfma_kernel<LAT><<<mb, TPB, 0, stream>>>(bufA, W2, bufB, n);
  quant_kernel<LAT><<<2048, TPB, 0, stream>>>(bufB, bufQ, scaleq, sdinv, dinv, n);
  gather_i8_kernel<LAT><<<(n * (LAT / 8) + TPB - 1) / TPB, TPB, 0, stream>>>(
      bufQ, scaleq, sdinv, rowptr, csr_src, dinv, b2, bufA, n);

  // mean pool
  pool2_kernel<<<GG, TPB, 0, stream>>>(bufA, gstart, out);
}

// Round 11
// 212.550 us; speedup vs baseline: 1.3940x; 1.0003x over previous
//
#include <hip/hip_runtime.h>

#define TPB 256
constexpr int DIN = 47;
constexpr int HID = 128;
constexpr int LAT = 64;
constexpr int GG  = 1024;
constexpr int NBMAX = 512;   // max dst-buckets (256 nodes each)
constexpr int PB  = 256;     // partition blocks

typedef __attribute__((ext_vector_type(8))) short short8v;
typedef __attribute__((ext_vector_type(4))) float float4v;

__device__ inline ushort f2bf(float f) {          // round-to-nearest-even bf16
  uint32_t u = __float_as_uint(f);
  return (ushort)((u + 0x7FFFu + ((u >> 16) & 1u)) >> 16);
}
__device__ inline float bf2f(ushort s) {
  return __uint_as_float(((uint32_t)s) << 16);
}

// ------- embed (MFMA): out[n,128] bf16 = relu( x[n,47]@W_emb[47,128] + b ) -------
// K padded 47->64 with zeros; A (x rows) and B (W^T) staged bf16 in LDS, XOR-swizzled.
__global__ __launch_bounds__(256) void embed_mfma_kernel(
    const float* __restrict__ x, const float* __restrict__ W,
    const float* __restrict__ b, ushort* __restrict__ out, int n) {
  __shared__ ushort Wt[HID * 64];       // [col][k] bf16, swizzled, k padded to 64
  __shared__ ushort xl[64 * 64];        // [node_local][k] bf16, swizzled
  __shared__ float bl[HID];
  const int tid = threadIdx.x;
  const int nb0 = blockIdx.x * 64;
  for (int i = tid; i < HID * 64; i += TPB) {
    int c = i & (HID - 1), k = i >> 7;
    ushort v = (k < DIN) ? f2bf(W[k * HID + c]) : (ushort)0;
    Wt[c * 64 + (k ^ ((c & 7) << 3))] = v;
  }
  for (int i = tid; i < 64 * 64; i += TPB) {
    int nl = i >> 6, k = i & 63;
    int node = nb0 + nl;
    ushort v = (k < DIN && node < n) ? f2bf(x[(size_t)node * DIN + k]) : (ushort)0;
    xl[nl * 64 + (k ^ ((nl & 7) << 3))] = v;
  }
  if (tid < HID) bl[tid] = b[tid];
  __syncthreads();
  const int lane = tid & 63, wave = tid >> 6;
  const int rowA = lane & 15, kgrp = lane >> 4;
  const int rl = wave * 16 + rowA;                 // local A row
  const int swa = (rl & 7) << 3;
  short8v a0 = *(const short8v*)&xl[rl * 64 + ((kgrp * 8)      ^ swa)];
  short8v a1 = *(const short8v*)&xl[rl * 64 + ((kgrp * 8 + 32) ^ swa)];
  #pragma unroll
  for (int ct = 0; ct < HID / 16; ++ct) {
    const int c = ct * 16 + rowA;
    const int sw = (c & 7) << 3;
    const ushort* wc = &Wt[c * 64];
    float4v acc = {0.f, 0.f, 0.f, 0.f};
    acc = __builtin_amdgcn_mfma_f32_16x16x32_bf16(a0, *(const short8v*)(wc + ((kgrp * 8)      ^ sw)), acc, 0, 0, 0);
    acc = __builtin_amdgcn_mfma_f32_16x16x32_bf16(a1, *(const short8v*)(wc + ((kgrp * 8 + 32) ^ sw)), acc, 0, 0, 0);
    float bc = bl[c];
    #pragma unroll
    for (int r = 0; r < 4; ++r) {
      int node = nb0 + wave * 16 + kgrp * 4 + r;
      if (node < n) out[(size_t)node * HID + c] = f2bf(fmaxf(acc[r] + bc, 0.f));
    }
  }
}

// ------- lin (MFMA): out[n,OD] bf16 = h[n,128] bf16 @ W[128,OD] fp32->bf16 -------
template <int OD>
__global__ __launch_bounds__(256) void lin_mfma_kernel(
    const ushort* __restrict__ h, const float* __restrict__ W,
    ushort* __restrict__ out, int n) {
  __shared__ ushort Wt[OD * 128];   // [col][k] bf16, swizzled
  const int tid = threadIdx.x;
  for (int idx = tid; idx < 128 * OD; idx += TPB) {
    int k = idx / OD, c = idx - k * OD;
    Wt[c * 128 + (k ^ ((c & 7) << 3))] = f2bf(W[idx]);
  }
  __syncthreads();
  const int lane = tid & 63, wave = tid >> 6;
  const int rowA = lane & 15, kgrp = lane >> 4;
  const int nb0 = blockIdx.x * 64 + wave * 16;
  int nodeA = nb0 + rowA; if (nodeA >= n) nodeA = n - 1;
  const ushort* hrow = h + (size_t)nodeA * 128 + kgrp * 8;
  short8v a0 = *(const short8v*)(hrow);
  short8v a1 = *(const short8v*)(hrow + 32);
  short8v a2 = *(const short8v*)(hrow + 64);
  short8v a3 = *(const short8v*)(hrow + 96);
  #pragma unroll
  for (int ct = 0; ct < OD / 16; ++ct) {
    const int c = ct * 16 + rowA;
    const int sw = (c & 7) << 3;
    const ushort* wc = &Wt[c * 128];
    float4v acc = {0.f, 0.f, 0.f, 0.f};
    acc = __builtin_amdgcn_mfma_f32_16x16x32_bf16(a0, *(const short8v*)(wc + ((kgrp * 8)       ^ sw)), acc, 0, 0, 0);
    acc = __builtin_amdgcn_mfma_f32_16x16x32_bf16(a1, *(const short8v*)(wc + ((kgrp * 8 + 32)  ^ sw)), acc, 0, 0, 0);
    acc = __builtin_amdgcn_mfma_f32_16x16x32_bf16(a2, *(const short8v*)(wc + ((kgrp * 8 + 64)  ^ sw)), acc, 0, 0, 0);
    acc = __builtin_amdgcn_mfma_f32_16x16x32_bf16(a3, *(const short8v*)(wc + ((kgrp * 8 + 96)  ^ sw)), acc, 0, 0, 0);
    #pragma unroll
    for (int r = 0; r < 4; ++r) {
      int node = nb0 + kgrp * 4 + r;
      if (node < n) out[(size_t)node * OD + c] = f2bf(acc[r]);
    }
  }
}

// ------- quant: bf16 rows -> biased int8 rows + scale, sdinv = scale*dinv -------
template <int OD>
__global__ __launch_bounds__(256) void quant_kernel(
    const ushort* __restrict__ hlin, unsigned char* __restrict__ q,
    float* __restrict__ scale, float* __restrict__ sdinv,
    const float* __restrict__ dinv, int n) {
  constexpr int CPL = OD / 16;                 // cols per lane: 8 or 4
  const int tid = threadIdx.x;
  const int grp = tid >> 4, L = tid & 15;
  for (int row = blockIdx.x * 16 + grp; row < n; row += gridDim.x * 16) {
    const ushort* hr = hlin + (size_t)row * OD + CPL * L;
    float v[CPL];
    #pragma unroll
    for (int c = 0; c < CPL; ++c) v[c] = bf2f(hr[c]);
    float m = 0.f;
    #pragma unroll
    for (int c = 0; c < CPL; ++c) m = fmaxf(m, fabsf(v[c]));
    #pragma unroll
    for (int o = 1; o < 16; o <<= 1) m = fmaxf(m, __shfl_xor(m, o, 16));
    float inv = (m > 0.f) ? 127.f / m : 0.f;
    unsigned int pk[CPL / 4];
    #pragma unroll
    for (int wq = 0; wq < CPL / 4; ++wq) {
      unsigned int p = 0;
      #pragma unroll
      for (int c = 0; c < 4; ++c) {
        int qv = (int)rintf(v[wq * 4 + c] * inv) + 128;
        p |= ((unsigned int)(qv & 255)) << (8 * c);
      }
      pk[wq] = p;
    }
    unsigned char* qr = q + (size_t)row * OD + CPL * L;
    if (CPL == 8) *(uint2*)qr = make_uint2(pk[0], pk[CPL / 4 - 1]);
    else          *(unsigned int*)qr = pk[0];
    if (L == 0) {
      float sc = m * (1.f / 127.f);
      scale[row] = sc;
      sdinv[row] = sc * dinv[row];
    }
  }
}

// ---------------- CSR build: two-level LDS counting sort (no global atomics) ----------------
__global__ __launch_bounds__(256) void histA_kernel(
    const int* __restrict__ dst, int* __restrict__ blockhist, int e, int nbuck) {
  __shared__ int hist[NBMAX];
  const int tid = threadIdx.x;
  for (int i = tid; i < nbuck; i += TPB) hist[i] = 0;
  __syncthreads();
  const int per = (e + PB - 1) / PB;
  const int lo = blockIdx.x * per;
  const int hi = min(lo + per, e);
  for (int i = lo + tid; i < hi; i += TPB)
    atomicAdd(&hist[dst[i] >> 8], 1);                 // LDS atomic
  __syncthreads();
  for (int i = tid; i < nbuck; i += TPB)
    blockhist[(size_t)i * PB + blockIdx.x] = hist[i]; // bucket-major
}

__global__ void scanG1_kernel(int* __restrict__ a, int* __restrict__ bsum, int m) {
  __shared__ int sh[TPB];
  int i = blockIdx.x * TPB + threadIdx.x;
  int v = (i < m) ? a[i] : 0;
  sh[threadIdx.x] = v;
  __syncthreads();
  for (int off = 1; off < TPB; off <<= 1) {
    int t = (threadIdx.x >= off) ? sh[threadIdx.x - off] : 0;
    __syncthreads();
    sh[threadIdx.x] += t;
    __syncthreads();
  }
  if (i < m) a[i] = sh[threadIdx.x] - v;
  if (threadIdx.x == TPB - 1) bsum[blockIdx.x] = sh[threadIdx.x];
}

__global__ void scan2_kernel(int* __restrict__ bsum, int nb) {
  __shared__ int sh[512];
  __shared__ int carry;
  if (threadIdx.x == 0) carry = 0;
  __syncthreads();
  for (int base = 0; base < nb; base += 512) {
    int i = base + threadIdx.x;
    int v = (i < nb) ? bsum[i] : 0;
    sh[threadIdx.x] = v;
    __syncthreads();
    for (int off = 1; off < 512; off <<= 1) {
      int t = (threadIdx.x >= off) ? sh[threadIdx.x - off] : 0;
      __syncthreads();
      sh[threadIdx.x] += t;
      __syncthreads();
    }
    if (i < nb) bsum[i] = carry + sh[threadIdx.x] - v;
    __syncthreads();
    if (threadIdx.x == 0) carry += sh[511];
    __syncthreads();
  }
}

__global__ void scanG3_kernel(int* __restrict__ a, const int* __restrict__ bsum, int m) {
  int i = blockIdx.x * TPB + threadIdx.x;
  if (i < m) a[i] += bsum[blockIdx.x];
}

__global__ __launch_bounds__(256) void scatterA_kernel(
    const int* __restrict__ src, const int* __restrict__ dst,
    const int* __restrict__ off, uint2* __restrict__ ppack, int e, int nbuck,
    const int* __restrict__ batch, int* __restrict__ gstart, int n, int G) {
  __shared__ int ofs[NBMAX];
  const int tid = threadIdx.x;
  for (int i = tid; i < nbuck; i += TPB)
    ofs[i] = off[(size_t)i * PB + blockIdx.x];
  __syncthreads();
  const int per = (e + PB - 1) / PB;
  const int lo = blockIdx.x * per;
  const int hi = min(lo + per, e);
  for (int i = lo + tid; i < hi; i += TPB) {
    int s = src[i], d = dst[i];
    int p = atomicAdd(&ofs[d >> 8], 1);               // LDS atomic
    ppack[p] = make_uint2((unsigned)s, (unsigned)d);
  }
  for (int i = blockIdx.x * TPB + tid; i < n; i += PB * TPB) {
    int bi = batch[i];
    int bp = (i == 0) ? -1 : batch[i - 1];
    for (int g = bp + 1; g <= bi; ++g) gstart[g] = i;
    if (i == n - 1)
      for (int g = bi + 1; g <= G; ++g) gstart[g] = n;
  }
}

__global__ __launch_bounds__(256) void bucketB_kernel(
    const uint2* __restrict__ ppack, const int* __restrict__ off,
    int* __restrict__ rowptr, float* __restrict__ dinv, int* __restrict__ csr_src,
    int n, int e, int nbuck) {
  __shared__ int cnt[256];
  __shared__ int sh[256];
  const int tid = threadIdx.x;
  const int b = blockIdx.x;
  const int bs = off[(size_t)b * PB];
  const int be = (b + 1 < nbuck) ? off[(size_t)(b + 1) * PB] : e;
  cnt[tid] = 0;
  __syncthreads();
  for (int i = bs + tid; i < be; i += TPB)
    atomicAdd(&cnt[ppack[i].y & 255], 1);             // LDS atomic
  __syncthreads();
  const int deg = cnt[tid];
  sh[tid] = deg;
  __syncthreads();
  for (int o = 1; o < 256; o <<= 1) {
    int t = (tid >= o) ? sh[tid - o] : 0;
    __syncthreads();
    sh[tid] += t;
    __syncthreads();
  }
  const int loff = sh[tid] - deg;                     // exclusive within bucket
  const int node = b * 256 + tid;
  if (node < n) {
    rowptr[node] = bs + loff;
    dinv[node] = rsqrtf((float)deg + 1.f);
  }
  if (b == nbuck - 1 && tid == TPB - 1) rowptr[n] = e;
  cnt[tid] = loff;                                    // running cursor
  __syncthreads();
  for (int i = bs + tid; i < be; i += TPB) {
    uint2 p = ppack[i];
    int pos = atomicAdd(&cnt[p.y & 255], 1);          // LDS atomic
    csr_src[bs + pos] = (int)p.x;
  }
}

// --- gather int8 rows (biased +128), fused finalize, bf16 out ---
template <int OD>
__global__ __launch_bounds__(256) void gather_i8_kernel(
    const unsigned char* __restrict__ q, const float* __restrict__ scale,
    const float* __restrict__ sdinv, const int* __restrict__ rowptr,
    const int* __restrict__ csr_src, const float* __restrict__ dinv,
    const float* __restrict__ b, ushort* __restrict__ out, int n) {
  constexpr int Q8 = OD / 8;                    // threads per node (16 or 8)
  constexpr int NS = TPB / Q8;
  const int tid = threadIdx.x;
  const int tx = tid & (Q8 - 1), slot = tid / Q8;
  int node = blockIdx.x * NS + slot;
  if (node >= n) return;
  const uint2* qrow = (const uint2*)q;
  int start = rowptr[node], end = rowptr[node + 1];
  float di = dinv[node];
  float acc[8];
  #pragma unroll
  for (int c = 0; c < 8; ++c) acc[c] = 0.f;
  float wsum = 0.f;
  int j = start;
  for (; j + 3 < end; j += 4) {
    int s[4]; uint2 v[4]; float w[4];
    #pragma unroll
    for (int u = 0; u < 4; ++u) s[u] = csr_src[j + u];
    #pragma unroll
    for (int u = 0; u < 4; ++u) v[u] = qrow[(size_t)s[u] * Q8 + tx];
    #pragma unroll
    for (int u = 0; u < 4; ++u) w[u] = sdinv[s[u]] * di;
    #pragma unroll
    for (int u = 0; u < 4; ++u) {
      wsum += w[u];
      acc[0] += w[u] * (float)( v[u].x        & 255u);
      acc[1] += w[u] * (float)((v[u].x >>  8) & 255u);
      acc[2] += w[u] * (float)((v[u].x >> 16) & 255u);
      acc[3] += w[u] * (float)( v[u].x >> 24);
      acc[4] += w[u] * (float)( v[u].y        & 255u);
      acc[5] += w[u] * (float)((v[u].y >>  8) & 255u);
      acc[6] += w[u] * (float)((v[u].y >> 16) & 255u);
      acc[7] += w[u] * (float)( v[u].y >> 24);
    }
  }
  for (; j < end; ++j) {
    int s0 = csr_src[j];
    uint2 v0 = qrow[(size_t)s0 * Q8 + tx];
    float w0 = sdinv[s0] * di;
    wsum += w0;
    acc[0] += w0 * (float)( v0.x        & 255u);
    acc[1] += w0 * (float)((v0.x >>  8) & 255u);
    acc[2] += w0 * (float)((v0.x >> 16) & 255u);
    acc[3] += w0 * (float)( v0.x >> 24);
    acc[4] += w0 * (float)( v0.y        & 255u);
    acc[5] += w0 * (float)((v0.y >>  8) & 255u);
    acc[6] += w0 * (float)((v0.y >> 16) & 255u);
    acc[7] += w0 * (float)( v0.y >> 24);
  }
  uint2 sv = qrow[(size_t)node * Q8 + tx];
  float ss = scale[node] * di * di;
  float su[8];
  su[0] = (float)( sv.x        & 255u); su[1] = (float)((sv.x >>  8) & 255u);
  su[2] = (float)((sv.x >> 16) & 255u); su[3] = (float)( sv.x >> 24);
  su[4] = (float)( sv.y        & 255u); su[5] = (float)((sv.y >>  8) & 255u);
  su[6] = (float)((sv.y >> 16) & 255u); su[7] = (float)( sv.y >> 24);
  float4 b0 = *(const float4*)(b + 8 * tx);
  float4 b1 = *(const float4*)(b + 8 * tx + 4);
  float bb[8] = {b0.x, b0.y, b0.z, b0.w, b1.x, b1.y, b1.z, b1.w};
  short8v o;
  #pragma unroll
  for (int c = 0; c < 8; ++c) {
    float val = acc[c] - 128.f * wsum + ss * (su[c] - 128.f) + bb[c];
    o[c] = (short)f2bf(fmaxf(val, 0.f));
  }
  *(short8v*)(out + (size_t)node * OD + 8 * tx) = o;
}

// ---------------- pool: batch sorted -> segment mean (bf16 in, fp32 out) ----------------
__global__ __launch_bounds__(256) void pool2_kernel(
    const ushort* __restrict__ h, const int* __restrict__ gstart,
    float* __restrict__ out) {
  __shared__ float sh[4][LAT];
  int g = blockIdx.x;
  int s = gstart[g], epos = gstart[g + 1];
  int c = threadIdx.x & (LAT - 1), r = threadIdx.x >> 6;
  float acc = 0.f;
  for (int i = s + r; i < epos; i += 4)
    acc += bf2f(h[(size_t)i * LAT + c]);
  sh[r][c] = acc;
  __syncthreads();
  if (r == 0) {
    float v = sh[0][c] + sh[1][c] + sh[2][c] + sh[3][c];
    out[(size_t)g * LAT + c] = v / fmaxf((float)(epos - s), 1.f);
  }
}

extern "C" void kernel_launch(void* const* d_in, const int* in_sizes, int n_in,
                              void* d_out, int out_size, void* d_ws, size_t ws_size,
                              hipStream_t stream) {
  const float* x     = (const float*)d_in[0];
  const float* W_emb = (const float*)d_in[1];
  const float* b_emb = (const float*)d_in[2];
  const float* W1    = (const float*)d_in[3];
  const float* b1    = (const float*)d_in[4];
  const float* W2    = (const float*)d_in[5];
  const float* b2    = (const float*)d_in[6];
  const int*   ei    = (const int*)d_in[7];
  const int*   batch = (const int*)d_in[8];
  const int n = in_sizes[8];
  const int e = in_sizes[7] / 2;
  const int* srcp = ei;
  const int* dstp = ei + e;
  float* out = (float*)d_out;

  char* ws = (char*)d_ws;
  size_t off_ = 0;
  auto alloc = [&](size_t bytes) {
    void* p = ws + off_;
    off_ += (bytes + 255) & ~(size_t)255;
    return p;
  };
  ushort* bufA    = (ushort*)alloc((size_t)n * HID * 2);        // h0/h1/h2 bf16
  ushort* bufB    = (ushort*)alloc((size_t)n * HID * 2);        // hlin bf16
  unsigned char* bufQ = (unsigned char*)alloc((size_t)n * HID); // int8 rows
  float*  scaleq  = (float*)alloc((size_t)n * 4);
  float*  sdinv   = (float*)alloc((size_t)n * 4);
  float*  dinv    = (float*)alloc((size_t)n * 4);
  int*    blockhist = (int*)alloc((size_t)NBMAX * PB * 4);      // bucket-major hist -> offsets
  int*    rowptr  = (int*)alloc((size_t)(n + 1) * 4);
  int*    bsum    = (int*)alloc((size_t)512 * 4);
  uint2*  ppack   = (uint2*)alloc((size_t)e * 8);               // partitioned (src,dst)
  int*    csr_src = (int*)alloc((size_t)e * 4);
  int*    gstart  = (int*)alloc((size_t)(GG + 1) * 4);

  const int nbuck = (n + 255) / 256;                 // 391
  const int m = nbuck * PB;                          // scan length
  const int mb2 = (m + TPB - 1) / TPB;
  const int mb = (n + 63) / 64;

  // h0 = relu(x @ W_emb + b_emb) -> bufA (MFMA, K padded to 64)
  embed_mfma_kernel<<<mb, TPB, 0, stream>>>(x, W_emb, b_emb, bufA, n);

  // CSR build: hist -> scan -> scatter -> per-bucket sort (LDS atomics only)
  histA_kernel<<<PB, TPB, 0, stream>>>(dstp, blockhist, e, nbuck);
  scanG1_kernel<<<mb2, TPB, 0, stream>>>(blockhist, bsum, m);
  scan2_kernel<<<1, 512, 0, stream>>>(bsum, mb2);
  scanG3_kernel<<<mb2, TPB, 0, stream>>>(blockhist, bsum, m);
  scatterA_kernel<<<PB, TPB, 0, stream>>>(srcp, dstp, blockhist, ppack, e, nbuck,
                                          batch, gstart, n, GG);
  bucketB_kernel<<<nbuck, TPB, 0, stream>>>(ppack, blockhist, rowptr, dinv, csr_src,
                                            n, e, nbuck);

  // conv1: lin -> bufB; quant -> bufQ; gather(int8) -> bufA
  lin_mfma_kernel<HID><<<mb, TPB, 0, stream>>>(bufA, W1, bufB, n);
  quant_kernel<HID><<<2048, TPB, 0, stream>>>(bufB, bufQ, scaleq, sdinv, dinv, n);
  gather_i8_kernel<HID><<<(n * (HID / 8) + TPB - 1) / TPB, TPB, 0, stream>>>(
      bufQ, scaleq, sdinv, rowptr, csr_src, dinv, b1, bufA, n);

  // conv2: lin -> bufB (n x 64); quant; gather(int8) -> bufA (n x 64)
  lin_mfma_kernel<LAT><<<mb, TPB, 0, stream>>>(bufA, W2, bufB, n);
  quant_kernel<LAT><<<2048, TPB, 0, stream>>>(bufB, bufQ, scaleq, sdinv, dinv, n);
  gather_i8_kernel<LAT><<<(n * (LAT / 8) + TPB - 1) / TPB, TPB, 0, stream>>>(
      bufQ, scaleq, sdinv, rowptr, csr_src, dinv, b2, bufA, n);

  // mean pool
  pool2_kernel<<<GG, TPB, 0, stream>>>(bufA, gstart, out);
}

// Round 12
// 200.776 us; speedup vs baseline: 1.4758x; 1.0586x over previous
//
#include <hip/hip_runtime.h>

#define TPB 256
constexpr int DIN = 47;
constexpr int HID = 128;
constexpr int LAT = 64;
constexpr int GG  = 1024;
constexpr int NBMAX = 512;   // max dst-buckets (256 nodes each)
constexpr int PB  = 256;     // partition blocks

typedef __attribute__((ext_vector_type(8))) short short8v;
typedef __attribute__((ext_vector_type(4))) float float4v;

__device__ inline ushort f2bf(float f) {          // round-to-nearest-even bf16
  uint32_t u = __float_as_uint(f);
  return (ushort)((u + 0x7FFFu + ((u >> 16) & 1u)) >> 16);
}
__device__ inline float bf2f(ushort s) {
  return __uint_as_float(((uint32_t)s) << 16);
}

// ------- embed (MFMA): out[n,128] bf16 = relu( x[n,47]@W_emb[47,128] + b ) -------
// A fragments loaded DIRECTLY from global fp32 (converted in registers, K padded to 64);
// W^T staged bf16 in LDS once per block; grid-stride over 64-node tiles.
__global__ __launch_bounds__(256) void embed_mfma_kernel(
    const float* __restrict__ x, const float* __restrict__ W,
    const float* __restrict__ b, ushort* __restrict__ out, int n) {
  __shared__ ushort Wt[HID * 64];       // [col][k] bf16, swizzled, k padded to 64
  __shared__ float bl[HID];
  const int tid = threadIdx.x;
  for (int i = tid; i < HID * 64; i += TPB) {   // coalesced W read; once per block
    int c = i & (HID - 1), k = i >> 7;
    ushort v = (k < DIN) ? f2bf(W[k * HID + c]) : (ushort)0;
    Wt[c * 64 + (k ^ ((c & 7) << 3))] = v;
  }
  if (tid < HID) bl[tid] = b[tid];
  __syncthreads();
  const int lane = tid & 63, wave = tid >> 6;
  const int rowA = lane & 15, kgrp = lane >> 4;
  for (int nb0 = blockIdx.x * 64; nb0 < n; nb0 += gridDim.x * 64) {
    const int tbase = nb0 + wave * 16;
    int nodeA = tbase + rowA; if (nodeA >= n) nodeA = n - 1;
    const float* xr = x + (size_t)nodeA * DIN;
    short8v a0, a1;
    #pragma unroll
    for (int j = 0; j < 8; ++j) {
      int k0 = kgrp * 8 + j;                  // 0..31 < 47: always valid
      a0[j] = (short)f2bf(xr[k0]);
      int k1 = 32 + kgrp * 8 + j;             // 32..63: valid iff < 47
      a1[j] = (short)((k1 < DIN) ? f2bf(xr[k1]) : (ushort)0);
    }
    #pragma unroll
    for (int ct = 0; ct < HID / 16; ++ct) {
      const int c = ct * 16 + rowA;
      const int sw = (c & 7) << 3;
      const ushort* wc = &Wt[c * 64];
      float4v acc = {0.f, 0.f, 0.f, 0.f};
      acc = __builtin_amdgcn_mfma_f32_16x16x32_bf16(a0, *(const short8v*)(wc + ((kgrp * 8)      ^ sw)), acc, 0, 0, 0);
      acc = __builtin_amdgcn_mfma_f32_16x16x32_bf16(a1, *(const short8v*)(wc + ((kgrp * 8 + 32) ^ sw)), acc, 0, 0, 0);
      float bc = bl[c];
      #pragma unroll
      for (int r = 0; r < 4; ++r) {
        int node = tbase + kgrp * 4 + r;
        if (node < n) out[(size_t)node * HID + c] = f2bf(fmaxf(acc[r] + bc, 0.f));
      }
    }
  }
}

// ------- lin (MFMA): out[n,OD] bf16 = h[n,128] bf16 @ W[128,OD] fp32->bf16 -------
template <int OD>
__global__ __launch_bounds__(256) void lin_mfma_kernel(
    const ushort* __restrict__ h, const float* __restrict__ W,
    ushort* __restrict__ out, int n) {
  __shared__ ushort Wt[OD * 128];   // [col][k] bf16, swizzled
  const int tid = threadIdx.x;
  for (int idx = tid; idx < 128 * OD; idx += TPB) {
    int k = idx / OD, c = idx - k * OD;
    Wt[c * 128 + (k ^ ((c & 7) << 3))] = f2bf(W[idx]);
  }
  __syncthreads();
  const int lane = tid & 63, wave = tid >> 6;
  const int rowA = lane & 15, kgrp = lane >> 4;
  const int nb0 = blockIdx.x * 64 + wave * 16;
  int nodeA = nb0 + rowA; if (nodeA >= n) nodeA = n - 1;
  const ushort* hrow = h + (size_t)nodeA * 128 + kgrp * 8;
  short8v a0 = *(const short8v*)(hrow);
  short8v a1 = *(const short8v*)(hrow + 32);
  short8v a2 = *(const short8v*)(hrow + 64);
  short8v a3 = *(const short8v*)(hrow + 96);
  #pragma unroll
  for (int ct = 0; ct < OD / 16; ++ct) {
    const int c = ct * 16 + rowA;
    const int sw = (c & 7) << 3;
    const ushort* wc = &Wt[c * 128];
    float4v acc = {0.f, 0.f, 0.f, 0.f};
    acc = __builtin_amdgcn_mfma_f32_16x16x32_bf16(a0, *(const short8v*)(wc + ((kgrp * 8)       ^ sw)), acc, 0, 0, 0);
    acc = __builtin_amdgcn_mfma_f32_16x16x32_bf16(a1, *(const short8v*)(wc + ((kgrp * 8 + 32)  ^ sw)), acc, 0, 0, 0);
    acc = __builtin_amdgcn_mfma_f32_16x16x32_bf16(a2, *(const short8v*)(wc + ((kgrp * 8 + 64)  ^ sw)), acc, 0, 0, 0);
    acc = __builtin_amdgcn_mfma_f32_16x16x32_bf16(a3, *(const short8v*)(wc + ((kgrp * 8 + 96)  ^ sw)), acc, 0, 0, 0);
    #pragma unroll
    for (int r = 0; r < 4; ++r) {
      int node = nb0 + kgrp * 4 + r;
      if (node < n) out[(size_t)node * OD + c] = f2bf(acc[r]);
    }
  }
}

// ------- quant: bf16 rows -> biased int8 rows + scale, sdinv = scale*dinv -------
template <int OD>
__global__ __launch_bounds__(256) void quant_kernel(
    const ushort* __restrict__ hlin, unsigned char* __restrict__ q,
    float* __restrict__ scale, float* __restrict__ sdinv,
    const float* __restrict__ dinv, int n) {
  constexpr int CPL = OD / 16;                 // cols per lane: 8 or 4
  const int tid = threadIdx.x;
  const int grp = tid >> 4, L = tid & 15;
  for (int row = blockIdx.x * 16 + grp; row < n; row += gridDim.x * 16) {
    const ushort* hr = hlin + (size_t)row * OD + CPL * L;
    float v[CPL];
    #pragma unroll
    for (int c = 0; c < CPL; ++c) v[c] = bf2f(hr[c]);
    float m = 0.f;
    #pragma unroll
    for (int c = 0; c < CPL; ++c) m = fmaxf(m, fabsf(v[c]));
    #pragma unroll
    for (int o = 1; o < 16; o <<= 1) m = fmaxf(m, __shfl_xor(m, o, 16));
    float inv = (m > 0.f) ? 127.f / m : 0.f;
    unsigned int pk[CPL / 4];
    #pragma unroll
    for (int wq = 0; wq < CPL / 4; ++wq) {
      unsigned int p = 0;
      #pragma unroll
      for (int c = 0; c < 4; ++c) {
        int qv = (int)rintf(v[wq * 4 + c] * inv) + 128;
        p |= ((unsigned int)(qv & 255)) << (8 * c);
      }
      pk[wq] = p;
    }
    unsigned char* qr = q + (size_t)row * OD + CPL * L;
    if (CPL == 8) *(uint2*)qr = make_uint2(pk[0], pk[CPL / 4 - 1]);
    else          *(unsigned int*)qr = pk[0];
    if (L == 0) {
      float sc = m * (1.f / 127.f);
      scale[row] = sc;
      sdinv[row] = sc * dinv[row];
    }
  }
}

// ---------------- CSR build: two-level LDS counting sort (no global atomics) ----------------
__global__ __launch_bounds__(256) void histA_kernel(
    const int* __restrict__ dst, int* __restrict__ blockhist, int e, int nbuck) {
  __shared__ int hist[NBMAX];
  const int tid = threadIdx.x;
  for (int i = tid; i < nbuck; i += TPB) hist[i] = 0;
  __syncthreads();
  const int per = (e + PB - 1) / PB;
  const int lo = blockIdx.x * per;
  const int hi = min(lo + per, e);
  for (int i = lo + tid; i < hi; i += TPB)
    atomicAdd(&hist[dst[i] >> 8], 1);                 // LDS atomic
  __syncthreads();
  for (int i = tid; i < nbuck; i += TPB)
    blockhist[(size_t)i * PB + blockIdx.x] = hist[i]; // bucket-major
}

__global__ void scanG1_kernel(int* __restrict__ a, int* __restrict__ bsum, int m) {
  __shared__ int sh[TPB];
  int i = blockIdx.x * TPB + threadIdx.x;
  int v = (i < m) ? a[i] : 0;
  sh[threadIdx.x] = v;
  __syncthreads();
  for (int off = 1; off < TPB; off <<= 1) {
    int t = (threadIdx.x >= off) ? sh[threadIdx.x - off] : 0;
    __syncthreads();
    sh[threadIdx.x] += t;
    __syncthreads();
  }
  if (i < m) a[i] = sh[threadIdx.x] - v;
  if (threadIdx.x == TPB - 1) bsum[blockIdx.x] = sh[threadIdx.x];
}

__global__ void scan2_kernel(int* __restrict__ bsum, int nb) {
  __shared__ int sh[512];
  __shared__ int carry;
  if (threadIdx.x == 0) carry = 0;
  __syncthreads();
  for (int base = 0; base < nb; base += 512) {
    int i = base + threadIdx.x;
    int v = (i < nb) ? bsum[i] : 0;
    sh[threadIdx.x] = v;
    __syncthreads();
    for (int off = 1; off < 512; off <<= 1) {
      int t = (threadIdx.x >= off) ? sh[threadIdx.x - off] : 0;
      __syncthreads();
      sh[threadIdx.x] += t;
      __syncthreads();
    }
    if (i < nb) bsum[i] = carry + sh[threadIdx.x] - v;
    __syncthreads();
    if (threadIdx.x == 0) carry += sh[511];
    __syncthreads();
  }
}

__global__ void scanG3_kernel(int* __restrict__ a, const int* __restrict__ bsum, int m) {
  int i = blockIdx.x * TPB + threadIdx.x;
  if (i < m) a[i] += bsum[blockIdx.x];
}

__global__ __launch_bounds__(256) void scatterA_kernel(
    const int* __restrict__ src, const int* __restrict__ dst,
    const int* __restrict__ off, uint2* __restrict__ ppack, int e, int nbuck,
    const int* __restrict__ batch, int* __restrict__ gstart, int n, int G) {
  __shared__ int ofs[NBMAX];
  const int tid = threadIdx.x;
  for (int i = tid; i < nbuck; i += TPB)
    ofs[i] = off[(size_t)i * PB + blockIdx.x];
  __syncthreads();
  const int per = (e + PB - 1) / PB;
  const int lo = blockIdx.x * per;
  const int hi = min(lo + per, e);
  for (int i = lo + tid; i < hi; i += TPB) {
    int s = src[i], d = dst[i];
    int p = atomicAdd(&ofs[d >> 8], 1);               // LDS atomic
    ppack[p] = make_uint2((unsigned)s, (unsigned)d);
  }
  for (int i = blockIdx.x * TPB + tid; i < n; i += PB * TPB) {
    int bi = batch[i];
    int bp = (i == 0) ? -1 : batch[i - 1];
    for (int g = bp + 1; g <= bi; ++g) gstart[g] = i;
    if (i == n - 1)
      for (int g = bi + 1; g <= G; ++g) gstart[g] = n;
  }
}

__global__ __launch_bounds__(256) void bucketB_kernel(
    const uint2* __restrict__ ppack, const int* __restrict__ off,
    int* __restrict__ rowptr, float* __restrict__ dinv, int* __restrict__ csr_src,
    int n, int e, int nbuck) {
  __shared__ int cnt[256];
  __shared__ int sh[256];
  const int tid = threadIdx.x;
  const int b = blockIdx.x;
  const int bs = off[(size_t)b * PB];
  const int be = (b + 1 < nbuck) ? off[(size_t)(b + 1) * PB] : e;
  cnt[tid] = 0;
  __syncthreads();
  for (int i = bs + tid; i < be; i += TPB)
    atomicAdd(&cnt[ppack[i].y & 255], 1);             // LDS atomic
  __syncthreads();
  const int deg = cnt[tid];
  sh[tid] = deg;
  __syncthreads();
  for (int o = 1; o < 256; o <<= 1) {
    int t = (tid >= o) ? sh[tid - o] : 0;
    __syncthreads();
    sh[tid] += t;
    __syncthreads();
  }
  const int loff = sh[tid] - deg;                     // exclusive within bucket
  const int node = b * 256 + tid;
  if (node < n) {
    rowptr[node] = bs + loff;
    dinv[node] = rsqrtf((float)deg + 1.f);
  }
  if (b == nbuck - 1 && tid == TPB - 1) rowptr[n] = e;
  cnt[tid] = loff;                                    // running cursor
  __syncthreads();
  for (int i = bs + tid; i < be; i += TPB) {
    uint2 p = ppack[i];
    int pos = atomicAdd(&cnt[p.y & 255], 1);          // LDS atomic
    csr_src[bs + pos] = (int)p.x;
  }
}

// --- gather int8 rows (biased +128), fused finalize, bf16 out ---
template <int OD>
__global__ __launch_bounds__(256) void gather_i8_kernel(
    const unsigned char* __restrict__ q, const float* __restrict__ scale,
    const float* __restrict__ sdinv, const int* __restrict__ rowptr,
    const int* __restrict__ csr_src, const float* __restrict__ dinv,
    const float* __restrict__ b, ushort* __restrict__ out, int n) {
  constexpr int Q8 = OD / 8;                    // threads per node (16 or 8)
  constexpr int NS = TPB / Q8;
  const int tid = threadIdx.x;
  const int tx = tid & (Q8 - 1), slot = tid / Q8;
  int node = blockIdx.x * NS + slot;
  if (node >= n) return;
  const uint2* qrow = (const uint2*)q;
  int start = rowptr[node], end = rowptr[node + 1];
  float di = dinv[node];
  float acc[8];
  #pragma unroll
  for (int c = 0; c < 8; ++c) acc[c] = 0.f;
  float wsum = 0.f;
  int j = start;
  for (; j + 3 < end; j += 4) {
    int s[4]; uint2 v[4]; float w[4];
    #pragma unroll
    for (int u = 0; u < 4; ++u) s[u] = csr_src[j + u];
    #pragma unroll
    for (int u = 0; u < 4; ++u) v[u] = qrow[(size_t)s[u] * Q8 + tx];
    #pragma unroll
    for (int u = 0; u < 4; ++u) w[u] = sdinv[s[u]] * di;
    #pragma unroll
    for (int u = 0; u < 4; ++u) {
      wsum += w[u];
      acc[0] += w[u] * (float)( v[u].x        & 255u);
      acc[1] += w[u] * (float)((v[u].x >>  8) & 255u);
      acc[2] += w[u] * (float)((v[u].x >> 16) & 255u);
      acc[3] += w[u] * (float)( v[u].x >> 24);
      acc[4] += w[u] * (float)( v[u].y        & 255u);
      acc[5] += w[u] * (float)((v[u].y >>  8) & 255u);
      acc[6] += w[u] * (float)((v[u].y >> 16) & 255u);
      acc[7] += w[u] * (float)( v[u].y >> 24);
    }
  }
  for (; j < end; ++j) {
    int s0 = csr_src[j];
    uint2 v0 = qrow[(size_t)s0 * Q8 + tx];
    float w0 = sdinv[s0] * di;
    wsum += w0;
    acc[0] += w0 * (float)( v0.x        & 255u);
    acc[1] += w0 * (float)((v0.x >>  8) & 255u);
    acc[2] += w0 * (float)((v0.x >> 16) & 255u);
    acc[3] += w0 * (float)( v0.x >> 24);
    acc[4] += w0 * (float)( v0.y        & 255u);
    acc[5] += w0 * (float)((v0.y >>  8) & 255u);
    acc[6] += w0 * (float)((v0.y >> 16) & 255u);
    acc[7] += w0 * (float)( v0.y >> 24);
  }
  uint2 sv = qrow[(size_t)node * Q8 + tx];
  float ss = scale[node] * di * di;
  float su[8];
  su[0] = (float)( sv.x        & 255u); su[1] = (float)((sv.x >>  8) & 255u);
  su[2] = (float)((sv.x >> 16) & 255u); su[3] = (float)( sv.x >> 24);
  su[4] = (float)( sv.y        & 255u); su[5] = (float)((sv.y >>  8) & 255u);
  su[6] = (float)((sv.y >> 16) & 255u); su[7] = (float)( sv.y >> 24);
  float4 b0 = *(const float4*)(b + 8 * tx);
  float4 b1 = *(const float4*)(b + 8 * tx + 4);
  float bb[8] = {b0.x, b0.y, b0.z, b0.w, b1.x, b1.y, b1.z, b1.w};
  short8v o;
  #pragma unroll
  for (int c = 0; c < 8; ++c) {
    float val = acc[c] - 128.f * wsum + ss * (su[c] - 128.f) + bb[c];
    o[c] = (short)f2bf(fmaxf(val, 0.f));
  }
  *(short8v*)(out + (size_t)node * OD + 8 * tx) = o;
}

// ---------------- pool: batch sorted -> segment mean (bf16 in, fp32 out) ----------------
__global__ __launch_bounds__(256) void pool2_kernel(
    const ushort* __restrict__ h, const int* __restrict__ gstart,
    float* __restrict__ out) {
  __shared__ float sh[4][LAT];
  int g = blockIdx.x;
  int s = gstart[g], epos = gstart[g + 1];
  int c = threadIdx.x & (LAT - 1), r = threadIdx.x >> 6;
  float acc = 0.f;
  for (int i = s + r; i < epos; i += 4)
    acc += bf2f(h[(size_t)i * LAT + c]);
  sh[r][c] = acc;
  __syncthreads();
  if (r == 0) {
    float v = sh[0][c] + sh[1][c] + sh[2][c] + sh[3][c];
    out[(size_t)g * LAT + c] = v / fmaxf((float)(epos - s), 1.f);
  }
}

extern "C" void kernel_launch(void* const* d_in, const int* in_sizes, int n_in,
                              void* d_out, int out_size, void* d_ws, size_t ws_size,
                              hipStream_t stream) {
  const float* x     = (const float*)d_in[0];
  const float* W_emb = (const float*)d_in[1];
  const float* b_emb = (const float*)d_in[2];
  const float* W1    = (const float*)d_in[3];
  const float* b1    = (const float*)d_in[4];
  const float* W2    = (const float*)d_in[5];
  const float* b2    = (const float*)d_in[6];
  const int*   ei    = (const int*)d_in[7];
  const int*   batch = (const int*)d_in[8];
  const int n = in_sizes[8];
  const int e = in_sizes[7] / 2;
  const int* srcp = ei;
  const int* dstp = ei + e;
  float* out = (float*)d_out;

  char* ws = (char*)d_ws;
  size_t off_ = 0;
  auto alloc = [&](size_t bytes) {
    void* p = ws + off_;
    off_ += (bytes + 255) & ~(size_t)255;
    return p;
  };
  ushort* bufA    = (ushort*)alloc((size_t)n * HID * 2);        // h0/h1/h2 bf16
  ushort* bufB    = (ushort*)alloc((size_t)n * HID * 2);        // hlin bf16
  unsigned char* bufQ = (unsigned char*)alloc((size_t)n * HID); // int8 rows
  float*  scaleq  = (float*)alloc((size_t)n * 4);
  float*  sdinv   = (float*)alloc((size_t)n * 4);
  float*  dinv    = (float*)alloc((size_t)n * 4);
  int*    blockhist = (int*)alloc((size_t)NBMAX * PB * 4);      // bucket-major hist -> offsets
  int*    rowptr  = (int*)alloc((size_t)(n + 1) * 4);
  int*    bsum    = (int*)alloc((size_t)512 * 4);
  uint2*  ppack   = (uint2*)alloc((size_t)e * 8);               // partitioned (src,dst)
  int*    csr_src = (int*)alloc((size_t)e * 4);
  int*    gstart  = (int*)alloc((size_t)(GG + 1) * 4);

  const int nbuck = (n + 255) / 256;                 // 391
  const int m = nbuck * PB;                          // scan length
  const int mb2 = (m + TPB - 1) / TPB;
  const int mb = (n + 63) / 64;

  // h0 = relu(x @ W_emb + b_emb) -> bufA (MFMA, A direct from global, grid-stride)
  embed_mfma_kernel<<<512, TPB, 0, stream>>>(x, W_emb, b_emb, bufA, n);

  // CSR build: hist -> scan -> scatter -> per-bucket sort (LDS atomics only)
  histA_kernel<<<PB, TPB, 0, stream>>>(dstp, blockhist, e, nbuck);
  scanG1_kernel<<<mb2, TPB, 0, stream>>>(blockhist, bsum, m);
  scan2_kernel<<<1, 512, 0, stream>>>(bsum, mb2);
  scanG3_kernel<<<mb2, TPB, 0, stream>>>(blockhist, bsum, m);
  scatterA_kernel<<<PB, TPB, 0, stream>>>(srcp, dstp, blockhist, ppack, e, nbuck,
                                          batch, gstart, n, GG);
  bucketB_kernel<<<nbuck, TPB, 0, stream>>>(ppack, blockhist, rowptr, dinv, csr_src,
                                            n, e, nbuck);

  // conv1: lin -> bufB; quant -> bufQ; gather(int8) -> bufA
  lin_mfma_kernel<HID><<<mb, TPB, 0, stream>>>(bufA, W1, bufB, n);
  quant_kernel<HID><<<2048, TPB, 0, stream>>>(bufB, bufQ, scaleq, sdinv, dinv, n);
  gather_i8_kernel<HID><<<(n * (HID / 8) + TPB - 1) / TPB, TPB, 0, stream>>>(
      bufQ, scaleq, sdinv, rowptr, csr_src, dinv, b1, bufA, n);

  // conv2: lin -> bufB (n x 64); quant; gather(int8) -> bufA (n x 64)
  lin_mfma_kernel<LAT><<<mb, TPB, 0, stream>>>(bufA, W2, bufB, n);
  quant_kernel<LAT><<<2048, TPB, 0, stream>>>(bufB, bufQ, scaleq, sdinv, dinv, n);
  gather_i8_kernel<LAT><<<(n * (LAT / 8) + TPB - 1) / TPB, TPB, 0, stream>>>(
      bufQ, scaleq, sdinv, rowptr, csr_src, dinv, b2, bufA, n);

  // mean pool
  pool2_kernel<<<GG, TPB, 0, stream>>>(bufA, gstart, out);
}

// Round 13
// 187.224 us; speedup vs baseline: 1.5826x; 1.0724x over previous
//
#include <hip/hip_runtime.h>

#define TPB 256
constexpr int DIN = 47;
constexpr int HID = 128;
constexpr int LAT = 64;
constexpr int GG  = 1024;
constexpr int NBMAX = 512;
constexpr int PB  = 256;

typedef __attribute__((ext_vector_type(8))) short short8v;
typedef __attribute__((ext_vector_type(4))) float float4v;

__device__ inline ushort f2bf(float f) {
  uint32_t u = __float_as_uint(f);
  return (ushort)((u + 0x7FFFu + ((u >> 16) & 1u)) >> 16);
}
__device__ inline float bf2f(ushort s) {
  return __uint_as_float(((uint32_t)s) << 16);
}

// ------- embed (MFMA): h0[n,128] bf16 = relu(x@W_emb + b), true col order -------
__global__ __launch_bounds__(256) void embed_mfma_kernel(
    const float* __restrict__ x, const float* __restrict__ W,
    const float* __restrict__ b, ushort* __restrict__ out, int n) {
  __shared__ ushort Wt[HID * 64];
  __shared__ float bl[HID];
  const int tid = threadIdx.x;
  for (int i = tid; i < HID * 64; i += TPB) {
    int c = i & (HID - 1), k = i >> 7;
    ushort v = (k < DIN) ? f2bf(W[k * HID + c]) : (ushort)0;
    Wt[c * 64 + (k ^ ((c & 7) << 3))] = v;
  }
  if (tid < HID) bl[tid] = b[tid];
  __syncthreads();
  const int lane = tid & 63, wave = tid >> 6;
  const int rowA = lane & 15, kgrp = lane >> 4;
  for (int nb0 = blockIdx.x * 64; nb0 < n; nb0 += gridDim.x * 64) {
    const int tbase = nb0 + wave * 16;
    int nodeA = tbase + rowA; if (nodeA >= n) nodeA = n - 1;
    const float* xr = x + (size_t)nodeA * DIN;
    short8v a0, a1;
    #pragma unroll
    for (int j = 0; j < 8; ++j) {
      int k0 = kgrp * 8 + j;
      a0[j] = (short)f2bf(xr[k0]);
      int k1 = 32 + kgrp * 8 + j;
      a1[j] = (short)((k1 < DIN) ? f2bf(xr[k1]) : (ushort)0);
    }
    #pragma unroll
    for (int ct = 0; ct < HID / 16; ++ct) {
      const int c = ct * 16 + rowA;
      const int sw = (c & 7) << 3;
      const ushort* wc = &Wt[c * 64];
      float4v acc = {0.f, 0.f, 0.f, 0.f};
      acc = __builtin_amdgcn_mfma_f32_16x16x32_bf16(a0, *(const short8v*)(wc + ((kgrp * 8)      ^ sw)), acc, 0, 0, 0);
      acc = __builtin_amdgcn_mfma_f32_16x16x32_bf16(a1, *(const short8v*)(wc + ((kgrp * 8 + 32) ^ sw)), acc, 0, 0, 0);
      float bc = bl[c];
      #pragma unroll
      for (int r = 0; r < 4; ++r) {
        int node = tbase + kgrp * 4 + r;
        if (node < n) out[(size_t)node * HID + c] = f2bf(fmaxf(acc[r] + bc, 0.f));
      }
    }
  }
}

// ------- lin+quant fused (MFMA): q[n,OD] int8 (PERMUTED cols) + scale + sdinv -------
// storage col p holds true col pi(p); pi128(p)=16*(p&7)+(p>>3), pi64(p)=16*(p&3)+(p>>2).
// PERMW: stage W rows with pi128 (input h is pi128-permuted, i.e. conv2).
template <int OD, bool PERMW>
__global__ __launch_bounds__(256) void lin_q_kernel(
    const ushort* __restrict__ h, const float* __restrict__ W,
    unsigned char* __restrict__ q, float* __restrict__ scaleq,
    float* __restrict__ sdinv, const float* __restrict__ dinv, int n) {
  constexpr int NCT = OD / 16;      // col-tiles; bytes per lane per row
  __shared__ ushort Wt[OD * 128];
  const int tid = threadIdx.x;
  for (int idx = tid; idx < 128 * OD; idx += TPB) {
    int k = idx / OD, c = idx - k * OD;                 // true row k, coalesced read
    int ks = PERMW ? (8 * (k & 15) + (k >> 4)) : k;     // storage row
    Wt[c * 128 + (ks ^ ((c & 7) << 3))] = f2bf(W[idx]);
  }
  __syncthreads();
  const int lane = tid & 63, wave = tid >> 6;
  const int rowA = lane & 15, kgrp = lane >> 4;
  const int nb0 = blockIdx.x * 64 + wave * 16;
  int nodeA = nb0 + rowA; if (nodeA >= n) nodeA = n - 1;
  const ushort* hrow = h + (size_t)nodeA * 128 + kgrp * 8;
  short8v a0 = *(const short8v*)(hrow);
  short8v a1 = *(const short8v*)(hrow + 32);
  short8v a2 = *(const short8v*)(hrow + 64);
  short8v a3 = *(const short8v*)(hrow + 96);
  float accv[NCT][4];
  #pragma unroll
  for (int ct = 0; ct < NCT; ++ct) {
    const int c = ct * 16 + rowA;
    const int sw = (c & 7) << 3;
    const ushort* wc = &Wt[c * 128];
    float4v acc = {0.f, 0.f, 0.f, 0.f};
    acc = __builtin_amdgcn_mfma_f32_16x16x32_bf16(a0, *(const short8v*)(wc + ((kgrp * 8)       ^ sw)), acc, 0, 0, 0);
    acc = __builtin_amdgcn_mfma_f32_16x16x32_bf16(a1, *(const short8v*)(wc + ((kgrp * 8 + 32)  ^ sw)), acc, 0, 0, 0);
    acc = __builtin_amdgcn_mfma_f32_16x16x32_bf16(a2, *(const short8v*)(wc + ((kgrp * 8 + 64)  ^ sw)), acc, 0, 0, 0);
    acc = __builtin_amdgcn_mfma_f32_16x16x32_bf16(a3, *(const short8v*)(wc + ((kgrp * 8 + 96)  ^ sw)), acc, 0, 0, 0);
    #pragma unroll
    for (int r = 0; r < 4; ++r) accv[ct][r] = acc[r];
  }
  // per-row (node) quantization; row owned by 16 lanes (fixed kgrp)
  #pragma unroll
  for (int r = 0; r < 4; ++r) {
    float m = 0.f;
    #pragma unroll
    for (int ct = 0; ct < NCT; ++ct) m = fmaxf(m, fabsf(accv[ct][r]));
    m = fmaxf(m, __shfl_xor(m, 1));
    m = fmaxf(m, __shfl_xor(m, 2));
    m = fmaxf(m, __shfl_xor(m, 4));
    m = fmaxf(m, __shfl_xor(m, 8));
    float inv = (m > 0.f) ? 127.f / m : 0.f;
    unsigned int pk[NCT / 4];
    #pragma unroll
    for (int wq = 0; wq < NCT / 4; ++wq) {
      unsigned int p = 0;
      #pragma unroll
      for (int j = 0; j < 4; ++j) {
        int qv = (int)rintf(accv[wq * 4 + j][r] * inv) + 128;
        p |= ((unsigned int)(qv & 255)) << (8 * j);
      }
      pk[wq] = p;
    }
    int node = nb0 + kgrp * 4 + r;
    if (node < n) {
      unsigned char* qr = q + (size_t)node * OD + rowA * NCT;  // p = rowA*NCT + ct
      if (NCT == 8) *(uint2*)qr = make_uint2(pk[0], pk[NCT / 4 - 1]);
      else          *(unsigned int*)qr = pk[0];
      if (rowA == 0) {
        float sc = m * (1.f / 127.f);
        scaleq[node] = sc;
        sdinv[node] = sc * dinv[node];
      }
    }
  }
}

// ---------------- CSR build: two-level LDS counting sort ----------------
__global__ __launch_bounds__(256) void histA_kernel(
    const int* __restrict__ dst, int* __restrict__ blockhist, int e, int nbuck) {
  __shared__ int hist[NBMAX];
  const int tid = threadIdx.x;
  for (int i = tid; i < nbuck; i += TPB) hist[i] = 0;
  __syncthreads();
  const int per = (e + PB - 1) / PB;
  const int lo = blockIdx.x * per;
  const int hi = min(lo + per, e);
  for (int i = lo + tid; i < hi; i += TPB)
    atomicAdd(&hist[dst[i] >> 8], 1);
  __syncthreads();
  for (int i = tid; i < nbuck; i += TPB)
    blockhist[(size_t)i * PB + blockIdx.x] = hist[i];
}

__global__ void scanG1_kernel(int* __restrict__ a, int* __restrict__ bsum, int m) {
  __shared__ int sh[TPB];
  int i = blockIdx.x * TPB + threadIdx.x;
  int v = (i < m) ? a[i] : 0;
  sh[threadIdx.x] = v;
  __syncthreads();
  for (int off = 1; off < TPB; off <<= 1) {
    int t = (threadIdx.x >= off) ? sh[threadIdx.x - off] : 0;
    __syncthreads();
    sh[threadIdx.x] += t;
    __syncthreads();
  }
  if (i < m) a[i] = sh[threadIdx.x] - v;
  if (threadIdx.x == TPB - 1) bsum[blockIdx.x] = sh[threadIdx.x];
}

__global__ void scan2_kernel(int* __restrict__ bsum, int nb) {
  __shared__ int sh[512];
  __shared__ int carry;
  if (threadIdx.x == 0) carry = 0;
  __syncthreads();
  for (int base = 0; base < nb; base += 512) {
    int i = base + threadIdx.x;
    int v = (i < nb) ? bsum[i] : 0;
    sh[threadIdx.x] = v;
    __syncthreads();
    for (int off = 1; off < 512; off <<= 1) {
      int t = (threadIdx.x >= off) ? sh[threadIdx.x - off] : 0;
      __syncthreads();
      sh[threadIdx.x] += t;
      __syncthreads();
    }
    if (i < nb) bsum[i] = carry + sh[threadIdx.x] - v;
    __syncthreads();
    if (threadIdx.x == 0) carry += sh[511];
    __syncthreads();
  }
}

// scatter: ofs = blockhist[i*PB+blk] + bsum[i]  (scanG3 folded in)
__global__ __launch_bounds__(256) void scatterA_kernel(
    const int* __restrict__ src, const int* __restrict__ dst,
    const int* __restrict__ off, const int* __restrict__ bsum,
    uint2* __restrict__ ppack, int e, int nbuck,
    const int* __restrict__ batch, int* __restrict__ gstart, int n, int G) {
  __shared__ int ofs[NBMAX];
  const int tid = threadIdx.x;
  for (int i = tid; i < nbuck; i += TPB)
    ofs[i] = off[(size_t)i * PB + blockIdx.x] + bsum[i];
  __syncthreads();
  const int per = (e + PB - 1) / PB;
  const int lo = blockIdx.x * per;
  const int hi = min(lo + per, e);
  for (int i = lo + tid; i < hi; i += TPB) {
    int s = src[i], d = dst[i];
    int p = atomicAdd(&ofs[d >> 8], 1);
    ppack[p] = make_uint2((unsigned)s, (unsigned)d);
  }
  for (int i = blockIdx.x * TPB + tid; i < n; i += PB * TPB) {
    int bi = batch[i];
    int bp = (i == 0) ? -1 : batch[i - 1];
    for (int g = bp + 1; g <= bi; ++g) gstart[g] = i;
    if (i == n - 1)
      for (int g = bi + 1; g <= G; ++g) gstart[g] = n;
  }
}

__global__ __launch_bounds__(256) void bucketB_kernel(
    const uint2* __restrict__ ppack, const int* __restrict__ off,
    const int* __restrict__ bsum, int* __restrict__ rowptr,
    float* __restrict__ dinv, int* __restrict__ csr_src,
    int n, int e, int nbuck) {
  __shared__ int cnt[256];
  __shared__ int sh[256];
  const int tid = threadIdx.x;
  const int b = blockIdx.x;
  const int bs = off[(size_t)b * PB] + bsum[b];
  const int be = (b + 1 < nbuck) ? (off[(size_t)(b + 1) * PB] + bsum[b + 1]) : e;
  cnt[tid] = 0;
  __syncthreads();
  for (int i = bs + tid; i < be; i += TPB)
    atomicAdd(&cnt[ppack[i].y & 255], 1);
  __syncthreads();
  const int deg = cnt[tid];
  sh[tid] = deg;
  __syncthreads();
  for (int o = 1; o < 256; o <<= 1) {
    int t = (tid >= o) ? sh[tid - o] : 0;
    __syncthreads();
    sh[tid] += t;
    __syncthreads();
  }
  const int loff = sh[tid] - deg;
  const int node = b * 256 + tid;
  if (node < n) {
    rowptr[node] = bs + loff;
    dinv[node] = rsqrtf((float)deg + 1.f);
  }
  if (b == nbuck - 1 && tid == TPB - 1) rowptr[n] = e;
  cnt[tid] = loff;
  __syncthreads();
  for (int i = bs + tid; i < be; i += TPB) {
    uint2 p = ppack[i];
    int pos = atomicAdd(&cnt[p.y & 255], 1);
    csr_src[bs + pos] = (int)p.x;
  }
}

// --- gather int8 (permuted col storage), fused finalize, bf16 out (same perm order) ---
template <int OD>
__global__ __launch_bounds__(256) void gather_i8_kernel(
    const unsigned char* __restrict__ q, const float* __restrict__ scale,
    const float* __restrict__ sdinv, const int* __restrict__ rowptr,
    const int* __restrict__ csr_src, const float* __restrict__ dinv,
    const float* __restrict__ b, ushort* __restrict__ out, int n) {
  constexpr int Q8 = OD / 8;
  constexpr int NS = TPB / Q8;
  const int tid = threadIdx.x;
  const int tx = tid & (Q8 - 1), slot = tid / Q8;
  int node = blockIdx.x * NS + slot;
  if (node >= n) return;
  const uint2* qrow = (const uint2*)q;
  int start = rowptr[node], end = rowptr[node + 1];
  float di = dinv[node];
  float acc[8];
  #pragma unroll
  for (int c = 0; c < 8; ++c) acc[c] = 0.f;
  float wsum = 0.f;
  int j = start;
  for (; j + 3 < end; j += 4) {
    int s[4]; uint2 v[4]; float w[4];
    #pragma unroll
    for (int u = 0; u < 4; ++u) s[u] = csr_src[j + u];
    #pragma unroll
    for (int u = 0; u < 4; ++u) v[u] = qrow[(size_t)s[u] * Q8 + tx];
    #pragma unroll
    for (int u = 0; u < 4; ++u) w[u] = sdinv[s[u]];      // di hoisted out
    #pragma unroll
    for (int u = 0; u < 4; ++u) {
      wsum += w[u];
      acc[0] += w[u] * (float)( v[u].x        & 255u);
      acc[1] += w[u] * (float)((v[u].x >>  8) & 255u);
      acc[2] += w[u] * (float)((v[u].x >> 16) & 255u);
      acc[3] += w[u] * (float)( v[u].x >> 24);
      acc[4] += w[u] * (float)( v[u].y        & 255u);
      acc[5] += w[u] * (float)((v[u].y >>  8) & 255u);
      acc[6] += w[u] * (float)((v[u].y >> 16) & 255u);
      acc[7] += w[u] * (float)( v[u].y >> 24);
    }
  }
  for (; j < end; ++j) {
    int s0 = csr_src[j];
    uint2 v0 = qrow[(size_t)s0 * Q8 + tx];
    float w0 = sdinv[s0];
    wsum += w0;
    acc[0] += w0 * (float)( v0.x        & 255u);
    acc[1] += w0 * (float)((v0.x >>  8) & 255u);
    acc[2] += w0 * (float)((v0.x >> 16) & 255u);
    acc[3] += w0 * (float)( v0.x >> 24);
    acc[4] += w0 * (float)( v0.y        & 255u);
    acc[5] += w0 * (float)((v0.y >>  8) & 255u);
    acc[6] += w0 * (float)((v0.y >> 16) & 255u);
    acc[7] += w0 * (float)( v0.y >> 24);
  }
  uint2 sv = qrow[(size_t)node * Q8 + tx];
  float ss = scale[node] * di * di;
  float su[8];
  su[0] = (float)( sv.x        & 255u); su[1] = (float)((sv.x >>  8) & 255u);
  su[2] = (float)((sv.x >> 16) & 255u); su[3] = (float)( sv.x >> 24);
  su[4] = (float)( sv.y        & 255u); su[5] = (float)((sv.y >>  8) & 255u);
  su[6] = (float)((sv.y >> 16) & 255u); su[7] = (float)( sv.y >> 24);
  // bias at TRUE col of storage byte p = 8*tx + j
  float bb[8];
  #pragma unroll
  for (int j2 = 0; j2 < 8; ++j2) {
    int ctrue = (OD == 128) ? (16 * j2 + tx)
                            : (16 * (j2 & 3) + 2 * tx + (j2 >> 2));
    bb[j2] = b[ctrue];
  }
  short8v o;
  #pragma unroll
  for (int c = 0; c < 8; ++c) {
    float val = di * (acc[c] - 128.f * wsum) + ss * (su[c] - 128.f) + bb[c];
    o[c] = (short)f2bf(fmaxf(val, 0.f));
  }
  *(short8v*)(out + (size_t)node * OD + 8 * tx) = o;
}

// ---------------- pool: segment mean over pi2-permuted h2; unpermute on write ----------------
__global__ __launch_bounds__(256) void pool2_kernel(
    const ushort* __restrict__ h, const int* __restrict__ gstart,
    float* __restrict__ out) {
  __shared__ float sh[4][LAT];
  int g = blockIdx.x;
  int s = gstart[g], epos = gstart[g + 1];
  int c = threadIdx.x & (LAT - 1), r = threadIdx.x >> 6;
  float acc = 0.f;
  for (int i = s + r; i < epos; i += 4)
    acc += bf2f(h[(size_t)i * LAT + c]);
  sh[r][c] = acc;
  __syncthreads();
  if (r == 0) {
    float v = sh[0][c] + sh[1][c] + sh[2][c] + sh[3][c];
    int ctrue = 16 * (c & 3) + (c >> 2);        // pi64
    out[(size_t)g * LAT + ctrue] = v / fmaxf((float)(epos - s), 1.f);
  }
}

extern "C" void kernel_launch(void* const* d_in, const int* in_sizes, int n_in,
                              void* d_out, int out_size, void* d_ws, size_t ws_size,
                              hipStream_t stream) {
  const float* x     = (const float*)d_in[0];
  const float* W_emb = (const float*)d_in[1];
  const float* b_emb = (const float*)d_in[2];
  const float* W1    = (const float*)d_in[3];
  const float* b1    = (const float*)d_in[4];
  const float* W2    = (const float*)d_in[5];
  const float* b2    = (const float*)d_in[6];
  const int*   ei    = (const int*)d_in[7];
  const int*   batch = (const int*)d_in[8];
  const int n = in_sizes[8];
  const int e = in_sizes[7] / 2;
  const int* srcp = ei;
  const int* dstp = ei + e;
  float* out = (float*)d_out;

  char* ws = (char*)d_ws;
  size_t off_ = 0;
  auto alloc = [&](size_t bytes) {
    void* p = ws + off_;
    off_ += (bytes + 255) & ~(size_t)255;
    return p;
  };
  ushort* bufA    = (ushort*)alloc((size_t)n * HID * 2);        // h0 / h1_perm / h2_perm
  unsigned char* bufQ = (unsigned char*)alloc((size_t)n * HID); // int8 rows (perm)
  float*  scaleq  = (float*)alloc((size_t)n * 4);
  float*  sdinv   = (float*)alloc((size_t)n * 4);
  float*  dinv    = (float*)alloc((size_t)n * 4);
  int*    blockhist = (int*)alloc((size_t)NBMAX * PB * 4);
  int*    rowptr  = (int*)alloc((size_t)(n + 1) * 4);
  int*    bsum    = (int*)alloc((size_t)512 * 4);
  uint2*  ppack   = (uint2*)alloc((size_t)e * 8);
  int*    csr_src = (int*)alloc((size_t)e * 4);
  int*    gstart  = (int*)alloc((size_t)(GG + 1) * 4);

  const int nbuck = (n + 255) / 256;
  const int m = nbuck * PB;
  const int mb2 = (m + TPB - 1) / TPB;
  const int mb = (n + 63) / 64;

  // h0
  embed_mfma_kernel<<<512, TPB, 0, stream>>>(x, W_emb, b_emb, bufA, n);

  // CSR build (scanG3 folded into scatter/bucket)
  histA_kernel<<<PB, TPB, 0, stream>>>(dstp, blockhist, e, nbuck);
  scanG1_kernel<<<mb2, TPB, 0, stream>>>(blockhist, bsum, m);
  scan2_kernel<<<1, 512, 0, stream>>>(bsum, mb2);
  scatterA_kernel<<<PB, TPB, 0, stream>>>(srcp, dstp, blockhist, bsum, ppack, e, nbuck,
                                          batch, gstart, n, GG);
  bucketB_kernel<<<nbuck, TPB, 0, stream>>>(ppack, blockhist, bsum, rowptr, dinv,
                                            csr_src, n, e, nbuck);

  // conv1: lin+quant fused (h0 true order -> q1 perm) ; gather -> h1_perm
  lin_q_kernel<HID, false><<<mb, TPB, 0, stream>>>(bufA, W1, bufQ, scaleq, sdinv, dinv, n);
  gather_i8_kernel<HID><<<(n * (HID / 8) + TPB - 1) / TPB, TPB, 0, stream>>>(
      bufQ, scaleq, sdinv, rowptr, csr_src, dinv, b1, bufA, n);

  // conv2: lin+quant fused (h1_perm -> W2 rows permuted) ; gather -> h2_perm
  lin_q_kernel<LAT, true><<<mb, TPB, 0, stream>>>(bufA, W2, bufQ, scaleq, sdinv, dinv, n);
  gather_i8_kernel<LAT><<<(n * (LAT / 8) + TPB - 1) / TPB, TPB, 0, stream>>>(
      bufQ, scaleq, sdinv, rowptr, csr_src, dinv, b2, bufA, n);

  // pool (unpermutes pi64 on final write)
  pool2_kernel<<<GG, TPB, 0, stream>>>(bufA, gstart, out);
}

// Round 14
// 177.066 us; speedup vs baseline: 1.6734x; 1.0574x over previous
//
#include <hip/hip_runtime.h>

#define TPB 256
constexpr int DIN = 47;
constexpr int HID = 128;
constexpr int LAT = 64;
constexpr int GG  = 1024;
constexpr int NBMAX = 512;
constexpr int PB  = 512;     // edge partition slices (= embed grid)

typedef __attribute__((ext_vector_type(8))) short short8v;
typedef __attribute__((ext_vector_type(4))) float float4v;

__device__ inline ushort f2bf(float f) {
  uint32_t u = __float_as_uint(f);
  return (ushort)((u + 0x7FFFu + ((u >> 16) & 1u)) >> 16);
}
__device__ inline float bf2f(ushort s) {
  return __uint_as_float(((uint32_t)s) << 16);
}

// ------- embed (MFMA) + edge histogram fused -------
// h0[n,128] bf16 = relu(x@W_emb + b); blockhist[buck][PB] over dst>>8.
__global__ __launch_bounds__(256) void embed_hist_kernel(
    const float* __restrict__ x, const float* __restrict__ W,
    const float* __restrict__ b, ushort* __restrict__ out, int n,
    const int* __restrict__ dst, int* __restrict__ blockhist, int e, int nbuck) {
  __shared__ int hist[NBMAX];
  __shared__ ushort Wt[HID * 64];
  __shared__ float bl[HID];
  const int tid = threadIdx.x;
  for (int i = tid; i < nbuck; i += TPB) hist[i] = 0;
  __syncthreads();
  // histogram of this block's edge slice (LDS atomics)
  {
    const int per = (e + PB - 1) / PB;
    const int lo = blockIdx.x * per;
    const int hi = min(lo + per, e);
    for (int i = lo + tid; i < hi; i += TPB)
      atomicAdd(&hist[dst[i] >> 8], 1);
  }
  // stage W^T (bf16, swizzled) + bias
  for (int i = tid; i < HID * 64; i += TPB) {
    int c = i & (HID - 1), k = i >> 7;
    ushort v = (k < DIN) ? f2bf(W[k * HID + c]) : (ushort)0;
    Wt[c * 64 + (k ^ ((c & 7) << 3))] = v;
  }
  if (tid < HID) bl[tid] = b[tid];
  __syncthreads();
  for (int i = tid; i < nbuck; i += TPB)
    blockhist[(size_t)i * PB + blockIdx.x] = hist[i];
  // MFMA embed, grid-stride 64-node tiles
  const int lane = tid & 63, wave = tid >> 6;
  const int rowA = lane & 15, kgrp = lane >> 4;
  for (int nb0 = blockIdx.x * 64; nb0 < n; nb0 += gridDim.x * 64) {
    const int tbase = nb0 + wave * 16;
    int nodeA = tbase + rowA; if (nodeA >= n) nodeA = n - 1;
    const float* xr = x + (size_t)nodeA * DIN;
    short8v a0, a1;
    #pragma unroll
    for (int j = 0; j < 8; ++j) {
      int k0 = kgrp * 8 + j;
      a0[j] = (short)f2bf(xr[k0]);
      int k1 = 32 + kgrp * 8 + j;
      a1[j] = (short)((k1 < DIN) ? f2bf(xr[k1]) : (ushort)0);
    }
    #pragma unroll
    for (int ct = 0; ct < HID / 16; ++ct) {
      const int c = ct * 16 + rowA;
      const int sw = (c & 7) << 3;
      const ushort* wc = &Wt[c * 64];
      float4v acc = {0.f, 0.f, 0.f, 0.f};
      acc = __builtin_amdgcn_mfma_f32_16x16x32_bf16(a0, *(const short8v*)(wc + ((kgrp * 8)      ^ sw)), acc, 0, 0, 0);
      acc = __builtin_amdgcn_mfma_f32_16x16x32_bf16(a1, *(const short8v*)(wc + ((kgrp * 8 + 32) ^ sw)), acc, 0, 0, 0);
      float bc = bl[c];
      #pragma unroll
      for (int r = 0; r < 4; ++r) {
        int node = tbase + kgrp * 4 + r;
        if (node < n) out[(size_t)node * HID + c] = f2bf(fmaxf(acc[r] + bc, 0.f));
      }
    }
  }
}

// ------- lin+quant fused (MFMA): q[n,OD] int8 (PERMUTED cols) + scale + sdinv -------
template <int OD, bool PERMW>
__global__ __launch_bounds__(256) void lin_q_kernel(
    const ushort* __restrict__ h, const float* __restrict__ W,
    unsigned char* __restrict__ q, float* __restrict__ scaleq,
    float* __restrict__ sdinv, const float* __restrict__ dinv, int n) {
  constexpr int NCT = OD / 16;
  __shared__ ushort Wt[OD * 128];
  const int tid = threadIdx.x;
  for (int idx = tid; idx < 128 * OD; idx += TPB) {
    int k = idx / OD, c = idx - k * OD;
    int ks = PERMW ? (8 * (k & 15) + (k >> 4)) : k;
    Wt[c * 128 + (ks ^ ((c & 7) << 3))] = f2bf(W[idx]);
  }
  __syncthreads();
  const int lane = tid & 63, wave = tid >> 6;
  const int rowA = lane & 15, kgrp = lane >> 4;
  const int nb0 = blockIdx.x * 64 + wave * 16;
  int nodeA = nb0 + rowA; if (nodeA >= n) nodeA = n - 1;
  const ushort* hrow = h + (size_t)nodeA * 128 + kgrp * 8;
  short8v a0 = *(const short8v*)(hrow);
  short8v a1 = *(const short8v*)(hrow + 32);
  short8v a2 = *(const short8v*)(hrow + 64);
  short8v a3 = *(const short8v*)(hrow + 96);
  float accv[NCT][4];
  #pragma unroll
  for (int ct = 0; ct < NCT; ++ct) {
    const int c = ct * 16 + rowA;
    const int sw = (c & 7) << 3;
    const ushort* wc = &Wt[c * 128];
    float4v acc = {0.f, 0.f, 0.f, 0.f};
    acc = __builtin_amdgcn_mfma_f32_16x16x32_bf16(a0, *(const short8v*)(wc + ((kgrp * 8)       ^ sw)), acc, 0, 0, 0);
    acc = __builtin_amdgcn_mfma_f32_16x16x32_bf16(a1, *(const short8v*)(wc + ((kgrp * 8 + 32)  ^ sw)), acc, 0, 0, 0);
    acc = __builtin_amdgcn_mfma_f32_16x16x32_bf16(a2, *(const short8v*)(wc + ((kgrp * 8 + 64)  ^ sw)), acc, 0, 0, 0);
    acc = __builtin_amdgcn_mfma_f32_16x16x32_bf16(a3, *(const short8v*)(wc + ((kgrp * 8 + 96)  ^ sw)), acc, 0, 0, 0);
    #pragma unroll
    for (int r = 0; r < 4; ++r) accv[ct][r] = acc[r];
  }
  #pragma unroll
  for (int r = 0; r < 4; ++r) {
    float m = 0.f;
    #pragma unroll
    for (int ct = 0; ct < NCT; ++ct) m = fmaxf(m, fabsf(accv[ct][r]));
    m = fmaxf(m, __shfl_xor(m, 1));
    m = fmaxf(m, __shfl_xor(m, 2));
    m = fmaxf(m, __shfl_xor(m, 4));
    m = fmaxf(m, __shfl_xor(m, 8));
    float inv = (m > 0.f) ? 127.f / m : 0.f;
    unsigned int pk[NCT / 4];
    #pragma unroll
    for (int wq = 0; wq < NCT / 4; ++wq) {
      unsigned int p = 0;
      #pragma unroll
      for (int j = 0; j < 4; ++j) {
        int qv = (int)rintf(accv[wq * 4 + j][r] * inv) + 128;
        p |= ((unsigned int)(qv & 255)) << (8 * j);
      }
      pk[wq] = p;
    }
    int node = nb0 + kgrp * 4 + r;
    if (node < n) {
      unsigned char* qr = q + (size_t)node * OD + rowA * NCT;
      if (NCT == 8) *(uint2*)qr = make_uint2(pk[0], pk[NCT / 4 - 1]);
      else          *(unsigned int*)qr = pk[0];
      if (rowA == 0) {
        float sc = m * (1.f / 127.f);
        scaleq[node] = sc;
        sdinv[node] = sc * dinv[node];
      }
    }
  }
}

// ---------------- scan over m ints (block-local + single-block fixup) ----------------
__global__ void scanG1_kernel(int* __restrict__ a, int* __restrict__ bsum, int m) {
  __shared__ int sh[TPB];
  int i = blockIdx.x * TPB + threadIdx.x;
  int v = (i < m) ? a[i] : 0;
  sh[threadIdx.x] = v;
  __syncthreads();
  for (int off = 1; off < TPB; off <<= 1) {
    int t = (threadIdx.x >= off) ? sh[threadIdx.x - off] : 0;
    __syncthreads();
    sh[threadIdx.x] += t;
    __syncthreads();
  }
  if (i < m) a[i] = sh[threadIdx.x] - v;
  if (threadIdx.x == TPB - 1) bsum[blockIdx.x] = sh[threadIdx.x];
}

__global__ void scan2_kernel(int* __restrict__ bsum, int nb) {
  __shared__ int sh[512];
  __shared__ int carry;
  if (threadIdx.x == 0) carry = 0;
  __syncthreads();
  for (int base = 0; base < nb; base += 512) {
    int i = base + threadIdx.x;
    int v = (i < nb) ? bsum[i] : 0;
    sh[threadIdx.x] = v;
    __syncthreads();
    for (int off = 1; off < 512; off <<= 1) {
      int t = (threadIdx.x >= off) ? sh[threadIdx.x - off] : 0;
      __syncthreads();
      sh[threadIdx.x] += t;
      __syncthreads();
    }
    if (i < nb) bsum[i] = carry + sh[threadIdx.x] - v;
    __syncthreads();
    if (threadIdx.x == 0) carry += sh[511];
    __syncthreads();
  }
}

// scatter edges into bucket segments; packed uint32 (src<<8 | dst&255); gstart fused
__global__ __launch_bounds__(256) void scatterA_kernel(
    const int* __restrict__ src, const int* __restrict__ dst,
    const int* __restrict__ off, const int* __restrict__ bsum,
    unsigned int* __restrict__ ppack, int e, int nbuck,
    const int* __restrict__ batch, int* __restrict__ gstart, int n, int G) {
  __shared__ int ofs[NBMAX];
  const int tid = threadIdx.x;
  const int blk = blockIdx.x;
  for (int i = tid; i < nbuck; i += TPB) {
    size_t idx = (size_t)i * PB + blk;
    ofs[i] = off[idx] + bsum[idx >> 8];
  }
  __syncthreads();
  const int per = (e + PB - 1) / PB;
  const int lo = blk * per;
  const int hi = min(lo + per, e);
  for (int i = lo + tid; i < hi; i += TPB) {
    int s = src[i], d = dst[i];
    int p = atomicAdd(&ofs[d >> 8], 1);
    ppack[p] = ((unsigned)s << 8) | ((unsigned)d & 255u);
  }
  for (int i = blk * TPB + tid; i < n; i += PB * TPB) {
    int bi = batch[i];
    int bp = (i == 0) ? -1 : batch[i - 1];
    for (int g = bp + 1; g <= bi; ++g) gstart[g] = i;
    if (i == n - 1)
      for (int g = bi + 1; g <= G; ++g) gstart[g] = n;
  }
}

__global__ __launch_bounds__(256) void bucketB_kernel(
    const unsigned int* __restrict__ ppack, const int* __restrict__ off,
    const int* __restrict__ bsum, int* __restrict__ rowptr,
    float* __restrict__ dinv, int* __restrict__ csr_src,
    int n, int e, int nbuck) {
  __shared__ int cnt[256];
  __shared__ int sh[256];
  const int tid = threadIdx.x;
  const int b = blockIdx.x;
  const int bs = off[(size_t)b * PB] + bsum[((size_t)b * PB) >> 8];
  const int be = (b + 1 < nbuck)
      ? (off[(size_t)(b + 1) * PB] + bsum[((size_t)(b + 1) * PB) >> 8]) : e;
  cnt[tid] = 0;
  __syncthreads();
  for (int i = bs + tid; i < be; i += TPB)
    atomicAdd(&cnt[ppack[i] & 255u], 1);
  __syncthreads();
  const int deg = cnt[tid];
  sh[tid] = deg;
  __syncthreads();
  for (int o = 1; o < 256; o <<= 1) {
    int t = (tid >= o) ? sh[tid - o] : 0;
    __syncthreads();
    sh[tid] += t;
    __syncthreads();
  }
  const int loff = sh[tid] - deg;
  const int node = b * 256 + tid;
  if (node < n) {
    rowptr[node] = bs + loff;
    dinv[node] = rsqrtf((float)deg + 1.f);
  }
  if (b == nbuck - 1 && tid == TPB - 1) rowptr[n] = e;
  cnt[tid] = loff;
  __syncthreads();
  for (int i = bs + tid; i < be; i += TPB) {
    unsigned int p = ppack[i];
    int pos = atomicAdd(&cnt[p & 255u], 1);
    csr_src[bs + pos] = (int)(p >> 8);
  }
}

// --- gather int8 (permuted col storage), fused finalize, bf16 out (perm order) ---
template <int OD>
__global__ __launch_bounds__(256) void gather_i8_kernel(
    const unsigned char* __restrict__ q, const float* __restrict__ scale,
    const float* __restrict__ sdinv, const int* __restrict__ rowptr,
    const int* __restrict__ csr_src, const float* __restrict__ dinv,
    const float* __restrict__ b, ushort* __restrict__ out, int n) {
  constexpr int Q8 = OD / 8;
  constexpr int NS = TPB / Q8;
  const int tid = threadIdx.x;
  const int tx = tid & (Q8 - 1), slot = tid / Q8;
  int node = blockIdx.x * NS + slot;
  if (node >= n) return;
  const uint2* qrow = (const uint2*)q;
  int start = rowptr[node], end = rowptr[node + 1];
  float di = dinv[node];
  float acc[8];
  #pragma unroll
  for (int c = 0; c < 8; ++c) acc[c] = 0.f;
  float wsum = 0.f;
  int j = start;
  for (; j + 3 < end; j += 4) {
    int s[4]; uint2 v[4]; float w[4];
    #pragma unroll
    for (int u = 0; u < 4; ++u) s[u] = csr_src[j + u];
    #pragma unroll
    for (int u = 0; u < 4; ++u) v[u] = qrow[(size_t)s[u] * Q8 + tx];
    #pragma unroll
    for (int u = 0; u < 4; ++u) w[u] = sdinv[s[u]];
    #pragma unroll
    for (int u = 0; u < 4; ++u) {
      wsum += w[u];
      acc[0] += w[u] * (float)( v[u].x        & 255u);
      acc[1] += w[u] * (float)((v[u].x >>  8) & 255u);
      acc[2] += w[u] * (float)((v[u].x >> 16) & 255u);
      acc[3] += w[u] * (float)( v[u].x >> 24);
      acc[4] += w[u] * (float)( v[u].y        & 255u);
      acc[5] += w[u] * (float)((v[u].y >>  8) & 255u);
      acc[6] += w[u] * (float)((v[u].y >> 16) & 255u);
      acc[7] += w[u] * (float)( v[u].y >> 24);
    }
  }
  for (; j < end; ++j) {
    int s0 = csr_src[j];
    uint2 v0 = qrow[(size_t)s0 * Q8 + tx];
    float w0 = sdinv[s0];
    wsum += w0;
    acc[0] += w0 * (float)( v0.x        & 255u);
    acc[1] += w0 * (float)((v0.x >>  8) & 255u);
    acc[2] += w0 * (float)((v0.x >> 16) & 255u);
    acc[3] += w0 * (float)( v0.x >> 24);
    acc[4] += w0 * (float)( v0.y        & 255u);
    acc[5] += w0 * (float)((v0.y >>  8) & 255u);
    acc[6] += w0 * (float)((v0.y >> 16) & 255u);
    acc[7] += w0 * (float)( v0.y >> 24);
  }
  uint2 sv = qrow[(size_t)node * Q8 + tx];
  float ss = scale[node] * di * di;
  float su[8];
  su[0] = (float)( sv.x        & 255u); su[1] = (float)((sv.x >>  8) & 255u);
  su[2] = (float)((sv.x >> 16) & 255u); su[3] = (float)( sv.x >> 24);
  su[4] = (float)( sv.y        & 255u); su[5] = (float)((sv.y >>  8) & 255u);
  su[6] = (float)((sv.y >> 16) & 255u); su[7] = (float)( sv.y >> 24);
  float bb[8];
  #pragma unroll
  for (int j2 = 0; j2 < 8; ++j2) {
    int ctrue = (OD == 128) ? (16 * j2 + tx)
                            : (16 * (j2 & 3) + 2 * tx + (j2 >> 2));
    bb[j2] = b[ctrue];
  }
  short8v o;
  #pragma unroll
  for (int c = 0; c < 8; ++c) {
    float val = di * (acc[c] - 128.f * wsum) + ss * (su[c] - 128.f) + bb[c];
    o[c] = (short)f2bf(fmaxf(val, 0.f));
  }
  *(short8v*)(out + (size_t)node * OD + 8 * tx) = o;
}

// ---------------- pool: vectorized segment mean over pi64-permuted h2 ----------------
__global__ __launch_bounds__(256) void pool2_kernel(
    const ushort* __restrict__ h, const int* __restrict__ gstart,
    float* __restrict__ out) {
  __shared__ float sh[32][LAT];
  int g = blockIdx.x;
  int s = gstart[g], epos = gstart[g + 1];
  int grp = threadIdx.x >> 3, oct = threadIdx.x & 7;
  float acc[8];
  #pragma unroll
  for (int j = 0; j < 8; ++j) acc[j] = 0.f;
  for (int i = s + grp; i < epos; i += 32) {
    uint4 v = *(const uint4*)(h + (size_t)i * LAT + oct * 8);
    const ushort* pv = (const ushort*)&v;
    #pragma unroll
    for (int j = 0; j < 8; ++j) acc[j] += bf2f(pv[j]);
  }
  #pragma unroll
  for (int j = 0; j < 8; ++j) sh[grp][oct * 8 + j] = acc[j];
  __syncthreads();
  if (threadIdx.x < LAT) {
    int c = threadIdx.x;
    float v = 0.f;
    #pragma unroll
    for (int k = 0; k < 32; ++k) v += sh[k][c];
    int ctrue = 16 * (c & 3) + (c >> 2);        // pi64
    out[(size_t)g * LAT + ctrue] = v / fmaxf((float)(epos - s), 1.f);
  }
}

extern "C" void kernel_launch(void* const* d_in, const int* in_sizes, int n_in,
                              void* d_out, int out_size, void* d_ws, size_t ws_size,
                              hipStream_t stream) {
  const float* x     = (const float*)d_in[0];
  const float* W_emb = (const float*)d_in[1];
  const float* b_emb = (const float*)d_in[2];
  const float* W1    = (const float*)d_in[3];
  const float* b1    = (const float*)d_in[4];
  const float* W2    = (const float*)d_in[5];
  const float* b2    = (const float*)d_in[6];
  const int*   ei    = (const int*)d_in[7];
  const int*   batch = (const int*)d_in[8];
  const int n = in_sizes[8];
  const int e = in_sizes[7] / 2;
  const int* srcp = ei;
  const int* dstp = ei + e;
  float* out = (float*)d_out;

  char* ws = (char*)d_ws;
  size_t off_ = 0;
  auto alloc = [&](size_t bytes) {
    void* p = ws + off_;
    off_ += (bytes + 255) & ~(size_t)255;
    return p;
  };
  ushort* bufA    = (ushort*)alloc((size_t)n * HID * 2);
  unsigned char* bufQ = (unsigned char*)alloc((size_t)n * HID);
  float*  scaleq  = (float*)alloc((size_t)n * 4);
  float*  sdinv   = (float*)alloc((size_t)n * 4);
  float*  dinv    = (float*)alloc((size_t)n * 4);
  int*    blockhist = (int*)alloc((size_t)NBMAX * PB * 4);
  int*    rowptr  = (int*)alloc((size_t)(n + 1) * 4);
  int*    bsum    = (int*)alloc((size_t)1024 * 4);
  unsigned int* ppack = (unsigned int*)alloc((size_t)e * 4);
  int*    csr_src = (int*)alloc((size_t)e * 4);
  int*    gstart  = (int*)alloc((size_t)(GG + 1) * 4);

  const int nbuck = (n + 255) / 256;           // 391
  const int m = nbuck * PB;                    // scan length (bucket-major)
  const int mb2 = (m + TPB - 1) / TPB;
  const int mb = (n + 63) / 64;

  // h0 (MFMA) + edge histogram, fused
  embed_hist_kernel<<<PB, TPB, 0, stream>>>(x, W_emb, b_emb, bufA, n,
                                            dstp, blockhist, e, nbuck);

  // scan; scatter (packed uint32); per-bucket sort
  scanG1_kernel<<<mb2, TPB, 0, stream>>>(blockhist, bsum, m);
  scan2_kernel<<<1, 512, 0, stream>>>(bsum, mb2);
  scatterA_kernel<<<PB, TPB, 0, stream>>>(srcp, dstp, blockhist, bsum, ppack, e, nbuck,
                                          batch, gstart, n, GG);
  bucketB_kernel<<<nbuck, TPB, 0, stream>>>(ppack, blockhist, bsum, rowptr, dinv,
                                            csr_src, n, e, nbuck);

  // conv1
  lin_q_kernel<HID, false><<<mb, TPB, 0, stream>>>(bufA, W1, bufQ, scaleq, sdinv, dinv, n);
  gather_i8_kernel<HID><<<(n * (HID / 8) + TPB - 1) / TPB, TPB, 0, stream>>>(
      bufQ, scaleq, sdinv, rowptr, csr_src, dinv, b1, bufA, n);

  // conv2
  lin_q_kernel<LAT, true><<<mb, TPB, 0, stream>>>(bufA, W2, bufQ, scaleq, sdinv, dinv, n);
  gather_i8_kernel<LAT><<<(n * (LAT / 8) + TPB - 1) / TPB, TPB, 0, stream>>>(
      bufQ, scaleq, sdinv, rowptr, csr_src, dinv, b2, bufA, n);

  // pool (vectorized; unpermutes pi64 on final write)
  pool2_kernel<<<GG, TPB, 0, stream>>>(bufA, gstart, out);
}